// Round 1
// baseline (1418.307 us; speedup 1.0000x reference)
//
#include <hip/hip_runtime.h>
#include <math.h>

// ---------------- problem constants ----------------
#define BB 8
#define LL 4096
#define BL (BB*LL)            // 32768
#define IN_SZ 1024
#define D_MODEL 256
#define D_INNER 512
#define D_STATE 16
#define DT_RANK 16
#define NCLS 2
#define NCHUNK 64
#define CLEN (LL/NCHUNK)      // 64

// ---------------- workspace layout (floats) ----------------
#define OFF_H     ((size_t)0)                       // BL*256
#define OFF_XZ    (OFF_H    + (size_t)BL*D_MODEL)   // BL*1024
#define OFF_UC    (OFF_XZ   + (size_t)BL*1024)      // BL*512
#define OFF_XDBL  (OFF_UC   + (size_t)BL*D_INNER)   // BL*48
#define OFF_DT    (OFF_XDBL + (size_t)BL*48)        // BL*512
#define OFF_HLOC  (OFF_DT   + (size_t)BL*D_INNER)   // B*NCHUNK*16*512
#define OFF_PP    (OFF_HLOC + (size_t)BB*NCHUNK*D_STATE*D_INNER)
#define OFF_POOL  (OFF_PP   + (size_t)BB*NCHUNK*D_STATE*D_INNER) // B*256

// =====================================================================
// Generic fp32 GEMM (NT): C[m,n] = sum_k A[m,k]*B[n,k]  (+bias, epilogue)
// BM=BN=128, BK=8, 256 threads, 8x8 per thread.
// EPI: 0 none, 1 gelu(exact), 2 softplus
// =====================================================================
template<int EPI>
__global__ __launch_bounds__(256) void gemm_nt(
    const float* __restrict__ A, int lda,
    const float* __restrict__ Bw, int ldb,
    float* __restrict__ C, int ldc,
    const float* __restrict__ bias,
    int M, int N, int K)
{
    const int BM = 128, BN = 128, BK = 8;
    __shared__ float As[BK][BM + 4];
    __shared__ float Bs[BK][BN + 4];
    const int tid = threadIdx.x;
    const int m0 = blockIdx.y * BM;
    const int n0 = blockIdx.x * BN;
    const int ty = tid >> 4;          // 0..15 -> m sub-tile
    const int tx = tid & 15;          // 0..15 -> n sub-tile

    float acc[8][8];
#pragma unroll
    for (int i = 0; i < 8; i++)
#pragma unroll
        for (int j = 0; j < 8; j++) acc[i][j] = 0.f;

    const int lrow = tid >> 1;        // 0..127
    const int lk4  = (tid & 1) * 4;   // 0 or 4

    for (int k0 = 0; k0 < K; k0 += BK) {
        float4 av, bv;
        {
            const float* p = A + (size_t)(m0 + lrow) * lda + k0 + lk4;
            av = *reinterpret_cast<const float4*>(p);
        }
        {
            int nn = n0 + lrow;
            if (nn < N) {
                const float* p = Bw + (size_t)nn * ldb + k0 + lk4;
                bv = *reinterpret_cast<const float4*>(p);
            } else {
                bv = make_float4(0.f, 0.f, 0.f, 0.f);
            }
        }
        __syncthreads();
        As[lk4 + 0][lrow] = av.x; As[lk4 + 1][lrow] = av.y;
        As[lk4 + 2][lrow] = av.z; As[lk4 + 3][lrow] = av.w;
        Bs[lk4 + 0][lrow] = bv.x; Bs[lk4 + 1][lrow] = bv.y;
        Bs[lk4 + 2][lrow] = bv.z; Bs[lk4 + 3][lrow] = bv.w;
        __syncthreads();

#pragma unroll
        for (int k = 0; k < BK; k++) {
            float a[8], b[8];
            float4 a0 = *reinterpret_cast<const float4*>(&As[k][ty * 8]);
            float4 a1 = *reinterpret_cast<const float4*>(&As[k][ty * 8 + 4]);
            float4 b0 = *reinterpret_cast<const float4*>(&Bs[k][tx * 8]);
            float4 b1 = *reinterpret_cast<const float4*>(&Bs[k][tx * 8 + 4]);
            a[0]=a0.x; a[1]=a0.y; a[2]=a0.z; a[3]=a0.w;
            a[4]=a1.x; a[5]=a1.y; a[6]=a1.z; a[7]=a1.w;
            b[0]=b0.x; b[1]=b0.y; b[2]=b0.z; b[3]=b0.w;
            b[4]=b1.x; b[5]=b1.y; b[6]=b1.z; b[7]=b1.w;
#pragma unroll
            for (int i = 0; i < 8; i++)
#pragma unroll
                for (int j = 0; j < 8; j++)
                    acc[i][j] = fmaf(a[i], b[j], acc[i][j]);
        }
    }

#pragma unroll
    for (int i = 0; i < 8; i++) {
        int row = m0 + ty * 8 + i;
#pragma unroll
        for (int j = 0; j < 8; j++) {
            int col = n0 + tx * 8 + j;
            if (col < N) {
                float v = acc[i][j];
                if (bias) v += bias[col];
                if (EPI == 1) v = 0.5f * v * (1.0f + erff(v * 0.70710678118654752f));
                else if (EPI == 2) v = (v > 20.f) ? v : log1pf(expf(v));
                C[(size_t)row * ldc + col] = v;
            }
        }
    }
}

// =====================================================================
// Depthwise causal conv (width 4) + SiLU.  u = xz[:, :, 0:512]
// =====================================================================
__global__ __launch_bounds__(256) void conv_silu(
    const float* __restrict__ xz, const float* __restrict__ cw,
    const float* __restrict__ cb, float* __restrict__ uc)
{
    int idx = blockIdx.x * 256 + threadIdx.x;
    if (idx >= BL * D_INNER) return;
    int d  = idx & (D_INNER - 1);
    int bl = idx >> 9;
    int l  = bl & (LL - 1);
    const float w0 = cw[d * 4 + 0], w1 = cw[d * 4 + 1];
    const float w2 = cw[d * 4 + 2], w3 = cw[d * 4 + 3];
    const float* up = xz + (size_t)bl * 1024 + d;
    float s = cb[d];
    s = fmaf(up[0], w3, s);
    if (l >= 1) s = fmaf(up[-1024], w2, s);
    if (l >= 2) s = fmaf(up[-2048], w1, s);
    if (l >= 3) s = fmaf(up[-3072], w0, s);
    s = s / (1.f + expf(-s));
    uc[idx] = s;
}

// =====================================================================
// Selective scan, chunked linear recurrence.
// pass1: per chunk, local scan from h=0; record end-state + decay product
// =====================================================================
__global__ __launch_bounds__(256) void scan_pass1(
    const float* __restrict__ dtb, const float* __restrict__ uc,
    const float* __restrict__ xdbl, const float* __restrict__ A_log,
    float* __restrict__ hloc, float* __restrict__ Pp)
{
    int d = blockIdx.x * 256 + threadIdx.x;
    int c = blockIdx.y;
    int b = blockIdx.z;
    float Ac[16];
#pragma unroll
    for (int s = 0; s < 16; s++) Ac[s] = -expf(A_log[d * 16 + s]);
    float h[16], P[16];
#pragma unroll
    for (int s = 0; s < 16; s++) { h[s] = 0.f; P[s] = 1.f; }
    int base = b * LL + c * CLEN;
    for (int t = 0; t < CLEN; t++) {
        int row = base + t;
        float dt = dtb[(size_t)row * 512 + d];
        float u  = uc[(size_t)row * 512 + d];
        float du = dt * u;
        const float4* xb = reinterpret_cast<const float4*>(xdbl + (size_t)row * 48 + 16);
        float Bv[16];
        float4 q;
        q = xb[0]; Bv[0]=q.x; Bv[1]=q.y; Bv[2]=q.z; Bv[3]=q.w;
        q = xb[1]; Bv[4]=q.x; Bv[5]=q.y; Bv[6]=q.z; Bv[7]=q.w;
        q = xb[2]; Bv[8]=q.x; Bv[9]=q.y; Bv[10]=q.z; Bv[11]=q.w;
        q = xb[3]; Bv[12]=q.x; Bv[13]=q.y; Bv[14]=q.z; Bv[15]=q.w;
#pragma unroll
        for (int s = 0; s < 16; s++) {
            float a = expf(dt * Ac[s]);
            h[s] = fmaf(a, h[s], du * Bv[s]);
            P[s] *= a;
        }
    }
    size_t o = ((size_t)(b * NCHUNK + c) * 16) * 512 + d;
#pragma unroll
    for (int s = 0; s < 16; s++) { hloc[o + (size_t)s * 512] = h[s]; Pp[o + (size_t)s * 512] = P[s]; }
}

// fixup: sequential across chunks; rewrite hloc[c] := true initial state of chunk c
__global__ __launch_bounds__(256) void scan_fixup(
    float* __restrict__ hloc, const float* __restrict__ Pp)
{
    int flat = blockIdx.x * 256 + threadIdx.x;   // B*16*512 = 65536
    int d  = flat & 511;
    int bs = flat >> 9;
    int b  = bs >> 4;
    int s  = bs & 15;
    float H = 0.f;
    for (int c = 0; c < NCHUNK; c++) {
        size_t idx = ((size_t)(b * NCHUNK + c) * 16 + s) * 512 + d;
        float hl = hloc[idx];
        float p  = Pp[idx];
        hloc[idx] = H;           // becomes init state for chunk c
        H = fmaf(p, H, hl);
    }
}

// pass2: replay with correct init; emit y_final = (y + u*Dskip)*silu(z), in-place over uc
__global__ __launch_bounds__(256) void scan_pass2(
    const float* __restrict__ dtb, float* __restrict__ uc,
    const float* __restrict__ xdbl, const float* __restrict__ xz,
    const float* __restrict__ A_log, const float* __restrict__ Dskip,
    const float* __restrict__ hinit)
{
    int d = blockIdx.x * 256 + threadIdx.x;
    int c = blockIdx.y;
    int b = blockIdx.z;
    float Ac[16];
#pragma unroll
    for (int s = 0; s < 16; s++) Ac[s] = -expf(A_log[d * 16 + s]);
    float h[16];
    size_t o = ((size_t)(b * NCHUNK + c) * 16) * 512 + d;
#pragma unroll
    for (int s = 0; s < 16; s++) h[s] = hinit[o + (size_t)s * 512];
    const float Dsk = Dskip[d];
    int base = b * LL + c * CLEN;
    for (int t = 0; t < CLEN; t++) {
        int row = base + t;
        float dt = dtb[(size_t)row * 512 + d];
        float u  = uc[(size_t)row * 512 + d];
        float du = dt * u;
        const float4* xb = reinterpret_cast<const float4*>(xdbl + (size_t)row * 48 + 16);
        float Bv[16], Cv[16];
        float4 q;
        q = xb[0]; Bv[0]=q.x; Bv[1]=q.y; Bv[2]=q.z; Bv[3]=q.w;
        q = xb[1]; Bv[4]=q.x; Bv[5]=q.y; Bv[6]=q.z; Bv[7]=q.w;
        q = xb[2]; Bv[8]=q.x; Bv[9]=q.y; Bv[10]=q.z; Bv[11]=q.w;
        q = xb[3]; Bv[12]=q.x; Bv[13]=q.y; Bv[14]=q.z; Bv[15]=q.w;
        q = xb[4]; Cv[0]=q.x; Cv[1]=q.y; Cv[2]=q.z; Cv[3]=q.w;
        q = xb[5]; Cv[4]=q.x; Cv[5]=q.y; Cv[6]=q.z; Cv[7]=q.w;
        q = xb[6]; Cv[8]=q.x; Cv[9]=q.y; Cv[10]=q.z; Cv[11]=q.w;
        q = xb[7]; Cv[12]=q.x; Cv[13]=q.y; Cv[14]=q.z; Cv[15]=q.w;
        float y = 0.f;
#pragma unroll
        for (int s = 0; s < 16; s++) {
            float a = expf(dt * Ac[s]);
            h[s] = fmaf(a, h[s], du * Bv[s]);
            y = fmaf(h[s], Cv[s], y);
        }
        float z = xz[(size_t)row * 1024 + 512 + d];
        float sz = z / (1.f + expf(-z));
        uc[(size_t)row * 512 + d] = (y + u * Dsk) * sz;
    }
}

// =====================================================================
// mean-pool over L (partial, atomics) + final fc3
// =====================================================================
__global__ __launch_bounds__(256) void pool_partial(
    const float* __restrict__ h2, float* __restrict__ pooled)
{
    int t = threadIdx.x;
    int chunk = blockIdx.x;          // 0..15
    int b = blockIdx.y;
    int l0 = chunk * (LL / 16);
    float s = 0.f;
    for (int l = l0; l < l0 + LL / 16; l++)
        s += h2[((size_t)b * LL + l) * D_MODEL + t];
    atomicAdd(&pooled[b * D_MODEL + t], s);
}

__global__ __launch_bounds__(256) void fc3_kernel(
    const float* __restrict__ pooled, const float* __restrict__ w,
    const float* __restrict__ bias, float* __restrict__ out)
{
    __shared__ float red[256];
    int t = threadIdx.x;
    int b = blockIdx.x;
    float p = pooled[b * D_MODEL + t] * (1.0f / LL);
    for (int c = 0; c < NCLS; c++) {
        red[t] = p * w[c * D_MODEL + t];
        __syncthreads();
        for (int off = 128; off > 0; off >>= 1) {
            if (t < off) red[t] += red[t + off];
            __syncthreads();
        }
        if (t == 0) out[b * NCLS + c] = red[0] + bias[c];
        __syncthreads();
    }
}

// =====================================================================
extern "C" void kernel_launch(void* const* d_in, const int* in_sizes, int n_in,
                              void* d_out, int out_size, void* d_ws, size_t ws_size,
                              hipStream_t stream)
{
    const float* x         = (const float*)d_in[0];
    const float* fc1_w     = (const float*)d_in[1];
    const float* fc1_b     = (const float*)d_in[2];
    const float* in_proj_w = (const float*)d_in[3];
    const float* conv_w    = (const float*)d_in[4];
    const float* conv_b    = (const float*)d_in[5];
    const float* x_proj_w  = (const float*)d_in[6];
    const float* dt_proj_w = (const float*)d_in[7];
    const float* dt_proj_b = (const float*)d_in[8];
    const float* A_log     = (const float*)d_in[9];
    const float* D_skip    = (const float*)d_in[10];
    const float* out_proj_w= (const float*)d_in[11];
    const float* fc3_w     = (const float*)d_in[12];
    const float* fc3_b     = (const float*)d_in[13];
    float* out = (float*)d_out;

    float* W = (float*)d_ws;
    float* h     = W + OFF_H;
    float* xz    = W + OFF_XZ;
    float* uc    = W + OFF_UC;
    float* xdbl  = W + OFF_XDBL;
    float* dtb   = W + OFF_DT;
    float* hloc  = W + OFF_HLOC;
    float* Pp    = W + OFF_PP;
    float* pooled= W + OFF_POOL;

    // 1. h = gelu(x @ fc1_w^T + b)           (32768,1024)x(256,1024) -> (32768,256)
    gemm_nt<1><<<dim3(2, 256), 256, 0, stream>>>(x, IN_SZ, fc1_w, IN_SZ, h, D_MODEL, fc1_b, BL, D_MODEL, IN_SZ);
    // 2. xz = h @ in_proj_w^T                (32768,256)x(1024,256) -> (32768,1024)
    gemm_nt<0><<<dim3(8, 256), 256, 0, stream>>>(h, D_MODEL, in_proj_w, D_MODEL, xz, 1024, nullptr, BL, 1024, D_MODEL);
    // 3. uc = silu(causal_conv(u) + conv_b)
    conv_silu<<<(BL * D_INNER) / 256, 256, 0, stream>>>(xz, conv_w, conv_b, uc);
    // 4. x_dbl = uc @ x_proj_w^T             (32768,512)x(48,512) -> (32768,48)
    gemm_nt<0><<<dim3(1, 256), 256, 0, stream>>>(uc, D_INNER, x_proj_w, D_INNER, xdbl, 48, nullptr, BL, 48, D_INNER);
    // 5. dt = softplus(x_dbl[:, :16] @ dt_proj_w^T + b)  -> (32768,512)
    gemm_nt<2><<<dim3(4, 256), 256, 0, stream>>>(xdbl, 48, dt_proj_w, DT_RANK, dtb, D_INNER, dt_proj_b, BL, D_INNER, DT_RANK);
    // 6-8. chunked selective scan (+ gating fused into pass2, writes over uc)
    scan_pass1<<<dim3(2, NCHUNK, BB), 256, 0, stream>>>(dtb, uc, xdbl, A_log, hloc, Pp);
    scan_fixup<<<256, 256, 0, stream>>>(hloc, Pp);
    scan_pass2<<<dim3(2, NCHUNK, BB), 256, 0, stream>>>(dtb, uc, xdbl, xz, A_log, D_skip, hloc);
    // 9. h = y @ out_proj_w^T                (32768,512)x(256,512) -> (32768,256)
    gemm_nt<0><<<dim3(2, 256), 256, 0, stream>>>(uc, D_INNER, out_proj_w, D_INNER, h, D_MODEL, nullptr, BL, D_MODEL, D_INNER);
    // 10-12. mean pool + fc3
    hipMemsetAsync(pooled, 0, BB * D_MODEL * sizeof(float), stream);
    pool_partial<<<dim3(16, BB), 256, 0, stream>>>(h, pooled);
    fc3_kernel<<<BB, 256, 0, stream>>>(pooled, fc3_w, fc3_b, out);
}

// Round 5
// 832.514 us; speedup vs baseline: 1.7036x; 1.7036x over previous
//
#include <hip/hip_runtime.h>
#include <math.h>

// ---------------- problem constants ----------------
#define BB 8
#define LL 4096
#define BL (BB*LL)            // 32768
#define IN_SZ 1024
#define D_MODEL 256
#define D_INNER 512
#define D_STATE 16
#define DT_RANK 16
#define NCLS 2
#define NCHUNK 64
#define CLEN (LL/NCHUNK)      // 64

// ---------------- workspace layout (floats) ----------------
#define OFF_H     ((size_t)0)                       // BL*256
#define OFF_XZ    (OFF_H    + (size_t)BL*D_MODEL)   // BL*1024
#define OFF_UC    (OFF_XZ   + (size_t)BL*1024)      // BL*512
#define OFF_XBC   (OFF_UC   + (size_t)BL*D_INNER)   // BL*32
#define OFF_DT    (OFF_XBC  + (size_t)BL*32)        // BL*512
#define OFF_HLOC  (OFF_DT   + (size_t)BL*D_INNER)   // B*NCHUNK*16*512
#define OFF_PP    (OFF_HLOC + (size_t)BB*NCHUNK*D_STATE*D_INNER)
#define OFF_WDT   (OFF_PP   + (size_t)BB*NCHUNK*D_STATE*D_INNER) // 512*512
#define OFF_POOL  (OFF_WDT  + (size_t)512*512)      // B*256

typedef __bf16 bf16x8 __attribute__((ext_vector_type(8)));
typedef float  f32x4  __attribute__((ext_vector_type(4)));

__device__ __forceinline__ short f2bf(float f) {
    union { float f; unsigned u; } v; v.f = f;
    unsigned r = (v.u + 0x7fffu + ((v.u >> 16) & 1u)) >> 16;
    return (short)r;
}
__device__ __forceinline__ int pack2(float lo, float hi) {
    return (int)((unsigned short)f2bf(lo) | ((unsigned)(unsigned short)f2bf(hi) << 16));
}

// =====================================================================
// bf16-MFMA NT GEMM: C[m,n] = sum_k A[m,k]*B[n,k]  (fp32 in/out, fp32 acc)
// BM=BN=128, BK=32, 256 threads = 4 waves (2x2 of 64x64).
// EPI: 0 none, 1 bias+gelu(exact), 2 bias+softplus
// BOUND: bounds-check N (B-staging rows and C columns)
// Requires M%128==0, K%32==0; N%128==0 unless BOUND.
// =====================================================================
template<int EPI, bool BOUND>
__global__ __launch_bounds__(256) void gemm_bf16(
    const float* __restrict__ A, int lda,
    const float* __restrict__ Bw, int ldb,
    float* __restrict__ C, int ldc,
    const float* __restrict__ bias,
    int N, int K)
{
    __shared__ short As[128 * 32];   // [row][k] bf16, 16B-slot swizzled
    __shared__ short Bs[128 * 32];

    const int tid  = threadIdx.x;
    const int m0   = blockIdx.y * 128;
    const int n0   = blockIdx.x * 128;
    const int wave = tid >> 6;
    const int lane = tid & 63;
    const int wr   = wave >> 1;       // wave row (0..1)
    const int wc   = wave & 1;        // wave col (0..1)
    const int r0   = lane & 15;       // row/col within 16-tile
    const int kgf  = lane >> 4;       // k-group of fragment (0..3)

    // staging map: slot s -> row = s>>2, kg = s&3 ; thread handles s=tid, tid+256
    const int srow = tid >> 2;        // 0..63
    const int skg  = tid & 3;

    // fragment LDS offsets (in shorts): slot swizzle = kg ^ ((row>>1)&3)
    const int fslot = kgf ^ ((r0 >> 1) & 3);
    const int abase = (wr * 64 + r0) * 32 + fslot * 8;
    const int bbase = (wc * 64 + r0) * 32 + fslot * 8;

    f32x4 acc[4][4];
#pragma unroll
    for (int i = 0; i < 4; i++)
#pragma unroll
        for (int j = 0; j < 4; j++) acc[i][j] = (f32x4){0.f, 0.f, 0.f, 0.f};

    for (int k0 = 0; k0 < K; k0 += 32) {
        float4 av0[2], av1[2], bv0[2], bv1[2];
#pragma unroll
        for (int h = 0; h < 2; h++) {
            int row = srow + h * 64;
            const float* pa = A + (size_t)(m0 + row) * lda + k0 + skg * 8;
            av0[h] = *reinterpret_cast<const float4*>(pa);
            av1[h] = *reinterpret_cast<const float4*>(pa + 4);
            int nn = n0 + row;
            if (!BOUND || nn < N) {
                const float* pb = Bw + (size_t)nn * ldb + k0 + skg * 8;
                bv0[h] = *reinterpret_cast<const float4*>(pb);
                bv1[h] = *reinterpret_cast<const float4*>(pb + 4);
            } else {
                bv0[h] = make_float4(0.f, 0.f, 0.f, 0.f);
                bv1[h] = make_float4(0.f, 0.f, 0.f, 0.f);
            }
        }
        __syncthreads();   // previous tile's frag reads done before overwrite
#pragma unroll
        for (int h = 0; h < 2; h++) {
            int row = srow + h * 64;
            int s = skg ^ ((row >> 1) & 3);
            int4 wa, wb;
            wa.x = pack2(av0[h].x, av0[h].y); wa.y = pack2(av0[h].z, av0[h].w);
            wa.z = pack2(av1[h].x, av1[h].y); wa.w = pack2(av1[h].z, av1[h].w);
            wb.x = pack2(bv0[h].x, bv0[h].y); wb.y = pack2(bv0[h].z, bv0[h].w);
            wb.z = pack2(bv1[h].x, bv1[h].y); wb.w = pack2(bv1[h].z, bv1[h].w);
            *reinterpret_cast<int4*>(&As[row * 32 + s * 8]) = wa;
            *reinterpret_cast<int4*>(&Bs[row * 32 + s * 8]) = wb;
        }
        __syncthreads();

        bf16x8 af[4], bfq[4];
#pragma unroll
        for (int mi = 0; mi < 4; mi++)
            af[mi] = *reinterpret_cast<const bf16x8*>(&As[abase + mi * 16 * 32]);
#pragma unroll
        for (int ni = 0; ni < 4; ni++)
            bfq[ni] = *reinterpret_cast<const bf16x8*>(&Bs[bbase + ni * 16 * 32]);
#pragma unroll
        for (int mi = 0; mi < 4; mi++)
#pragma unroll
            for (int ni = 0; ni < 4; ni++)
                acc[mi][ni] = __builtin_amdgcn_mfma_f32_16x16x32_bf16(
                    af[mi], bfq[ni], acc[mi][ni], 0, 0, 0);
    }

    // epilogue: C/D layout col = lane&15, row = (lane>>4)*4 + reg
#pragma unroll
    for (int mi = 0; mi < 4; mi++) {
#pragma unroll
        for (int ni = 0; ni < 4; ni++) {
            int col = n0 + wc * 64 + ni * 16 + r0;
            if (BOUND && col >= N) continue;
            float bb = (EPI != 0 && bias) ? bias[col] : 0.f;
#pragma unroll
            for (int j = 0; j < 4; j++) {
                int row = m0 + wr * 64 + mi * 16 + kgf * 4 + j;
                float v = acc[mi][ni][j];
                if (EPI == 1) { v += bb; v = 0.5f * v * (1.0f + erff(v * 0.70710678118654752f)); }
                else if (EPI == 2) { v += bb; v = (v > 20.f) ? v : log1pf(expf(v)); }
                C[(size_t)row * ldc + col] = v;
            }
        }
    }
}

// =====================================================================
// W_dt[e][d] = sum_r dt_proj_w[e][r] * x_proj_w[r][d]   (512x512, r<16)
// =====================================================================
__global__ __launch_bounds__(256) void wdt_kernel(
    const float* __restrict__ dtw, const float* __restrict__ xpw,
    float* __restrict__ wdt)
{
    int idx = blockIdx.x * 256 + threadIdx.x;     // 512*512
    int d = idx & 511;
    int e = idx >> 9;
    float s = 0.f;
#pragma unroll
    for (int r = 0; r < 16; r++)
        s = fmaf(dtw[e * 16 + r], xpw[r * 512 + d], s);
    wdt[idx] = s;
}

// =====================================================================
// Depthwise causal conv (width 4) + SiLU.  u = xz[:, :, 0:512]
// =====================================================================
__global__ __launch_bounds__(256) void conv_silu(
    const float* __restrict__ xz, const float* __restrict__ cw,
    const float* __restrict__ cb, float* __restrict__ uc)
{
    int idx = blockIdx.x * 256 + threadIdx.x;
    if (idx >= BL * D_INNER) return;
    int d  = idx & (D_INNER - 1);
    int bl = idx >> 9;
    int l  = bl & (LL - 1);
    const float w0 = cw[d * 4 + 0], w1 = cw[d * 4 + 1];
    const float w2 = cw[d * 4 + 2], w3 = cw[d * 4 + 3];
    const float* up = xz + (size_t)bl * 1024 + d;
    float s = cb[d];
    s = fmaf(up[0], w3, s);
    if (l >= 1) s = fmaf(up[-1024], w2, s);
    if (l >= 2) s = fmaf(up[-2048], w1, s);
    if (l >= 3) s = fmaf(up[-3072], w0, s);
    s = s / (1.f + expf(-s));
    uc[idx] = s;
}

// =====================================================================
// Selective scan, chunked linear recurrence. xbc layout: [row][32] (B|C)
// =====================================================================
__global__ __launch_bounds__(256) void scan_pass1(
    const float* __restrict__ dtb, const float* __restrict__ uc,
    const float* __restrict__ xbc, const float* __restrict__ A_log,
    float* __restrict__ hloc, float* __restrict__ Pp)
{
    int d = blockIdx.x * 256 + threadIdx.x;
    int c = blockIdx.y;
    int b = blockIdx.z;
    float Ac[16];
#pragma unroll
    for (int s = 0; s < 16; s++) Ac[s] = -expf(A_log[d * 16 + s]);
    float h[16], P[16];
#pragma unroll
    for (int s = 0; s < 16; s++) { h[s] = 0.f; P[s] = 1.f; }
    int base = b * LL + c * CLEN;
    for (int t = 0; t < CLEN; t++) {
        int row = base + t;
        float dt = dtb[(size_t)row * 512 + d];
        float u  = uc[(size_t)row * 512 + d];
        float du = dt * u;
        const float4* xb = reinterpret_cast<const float4*>(xbc + (size_t)row * 32);
        float Bv[16];
        float4 q;
        q = xb[0]; Bv[0]=q.x; Bv[1]=q.y; Bv[2]=q.z; Bv[3]=q.w;
        q = xb[1]; Bv[4]=q.x; Bv[5]=q.y; Bv[6]=q.z; Bv[7]=q.w;
        q = xb[2]; Bv[8]=q.x; Bv[9]=q.y; Bv[10]=q.z; Bv[11]=q.w;
        q = xb[3]; Bv[12]=q.x; Bv[13]=q.y; Bv[14]=q.z; Bv[15]=q.w;
#pragma unroll
        for (int s = 0; s < 16; s++) {
            float a = expf(dt * Ac[s]);
            h[s] = fmaf(a, h[s], du * Bv[s]);
            P[s] *= a;
        }
    }
    size_t o = ((size_t)(b * NCHUNK + c) * 16) * 512 + d;
#pragma unroll
    for (int s = 0; s < 16; s++) { hloc[o + (size_t)s * 512] = h[s]; Pp[o + (size_t)s * 512] = P[s]; }
}

// fixup: sequential across chunks; rewrite hloc[c] := true initial state of chunk c
__global__ __launch_bounds__(256) void scan_fixup(
    float* __restrict__ hloc, const float* __restrict__ Pp)
{
    int flat = blockIdx.x * 256 + threadIdx.x;   // B*16*512 = 65536
    int d  = flat & 511;
    int bs = flat >> 9;
    int b  = bs >> 4;
    int s  = bs & 15;
    float H = 0.f;
    for (int c = 0; c < NCHUNK; c++) {
        size_t idx = ((size_t)(b * NCHUNK + c) * 16 + s) * 512 + d;
        float hl = hloc[idx];
        float p  = Pp[idx];
        hloc[idx] = H;           // becomes init state for chunk c
        H = fmaf(p, H, hl);
    }
}

// pass2: replay with correct init; emit y_final = (y + u*Dskip)*silu(z), in-place over uc
__global__ __launch_bounds__(256) void scan_pass2(
    const float* __restrict__ dtb, float* __restrict__ uc,
    const float* __restrict__ xbc, const float* __restrict__ xz,
    const float* __restrict__ A_log, const float* __restrict__ Dskip,
    const float* __restrict__ hinit)
{
    int d = blockIdx.x * 256 + threadIdx.x;
    int c = blockIdx.y;
    int b = blockIdx.z;
    float Ac[16];
#pragma unroll
    for (int s = 0; s < 16; s++) Ac[s] = -expf(A_log[d * 16 + s]);
    float h[16];
    size_t o = ((size_t)(b * NCHUNK + c) * 16) * 512 + d;
#pragma unroll
    for (int s = 0; s < 16; s++) h[s] = hinit[o + (size_t)s * 512];
    const float Dsk = Dskip[d];
    int base = b * LL + c * CLEN;
    for (int t = 0; t < CLEN; t++) {
        int row = base + t;
        float dt = dtb[(size_t)row * 512 + d];
        float u  = uc[(size_t)row * 512 + d];
        float du = dt * u;
        const float4* xb = reinterpret_cast<const float4*>(xbc + (size_t)row * 32);
        float Bv[16], Cv[16];
        float4 q;
        q = xb[0]; Bv[0]=q.x; Bv[1]=q.y; Bv[2]=q.z; Bv[3]=q.w;
        q = xb[1]; Bv[4]=q.x; Bv[5]=q.y; Bv[6]=q.z; Bv[7]=q.w;
        q = xb[2]; Bv[8]=q.x; Bv[9]=q.y; Bv[10]=q.z; Bv[11]=q.w;
        q = xb[3]; Bv[12]=q.x; Bv[13]=q.y; Bv[14]=q.z; Bv[15]=q.w;
        q = xb[4]; Cv[0]=q.x; Cv[1]=q.y; Cv[2]=q.z; Cv[3]=q.w;
        q = xb[5]; Cv[4]=q.x; Cv[5]=q.y; Cv[6]=q.z; Cv[7]=q.w;
        q = xb[6]; Cv[8]=q.x; Cv[9]=q.y; Cv[10]=q.z; Cv[11]=q.w;
        q = xb[7]; Cv[12]=q.x; Cv[13]=q.y; Cv[14]=q.z; Cv[15]=q.w;
        float y = 0.f;
#pragma unroll
        for (int s = 0; s < 16; s++) {
            float a = expf(dt * Ac[s]);
            h[s] = fmaf(a, h[s], du * Bv[s]);
            y = fmaf(h[s], Cv[s], y);
        }
        float z = xz[(size_t)row * 1024 + 512 + d];
        float sz = z / (1.f + expf(-z));
        uc[(size_t)row * 512 + d] = (y + u * Dsk) * sz;
    }
}

// =====================================================================
// mean-pool over L (partial, atomics) + final fc3
// =====================================================================
__global__ __launch_bounds__(256) void pool_partial(
    const float* __restrict__ h2, float* __restrict__ pooled)
{
    int t = threadIdx.x;
    int chunk = blockIdx.x;          // 0..15
    int b = blockIdx.y;
    int l0 = chunk * (LL / 16);
    float s = 0.f;
    for (int l = l0; l < l0 + LL / 16; l++)
        s += h2[((size_t)b * LL + l) * D_MODEL + t];
    atomicAdd(&pooled[b * D_MODEL + t], s);
}

__global__ __launch_bounds__(256) void fc3_kernel(
    const float* __restrict__ pooled, const float* __restrict__ w,
    const float* __restrict__ bias, float* __restrict__ out)
{
    __shared__ float red[256];
    int t = threadIdx.x;
    int b = blockIdx.x;
    float p = pooled[b * D_MODEL + t] * (1.0f / LL);
    for (int c = 0; c < NCLS; c++) {
        red[t] = p * w[c * D_MODEL + t];
        __syncthreads();
        for (int off = 128; off > 0; off >>= 1) {
            if (t < off) red[t] += red[t + off];
            __syncthreads();
        }
        if (t == 0) out[b * NCLS + c] = red[0] + bias[c];
        __syncthreads();
    }
}

// =====================================================================
extern "C" void kernel_launch(void* const* d_in, const int* in_sizes, int n_in,
                              void* d_out, int out_size, void* d_ws, size_t ws_size,
                              hipStream_t stream)
{
    const float* x         = (const float*)d_in[0];
    const float* fc1_w     = (const float*)d_in[1];
    const float* fc1_b     = (const float*)d_in[2];
    const float* in_proj_w = (const float*)d_in[3];
    const float* conv_w    = (const float*)d_in[4];
    const float* conv_b    = (const float*)d_in[5];
    const float* x_proj_w  = (const float*)d_in[6];
    const float* dt_proj_w = (const float*)d_in[7];
    const float* dt_proj_b = (const float*)d_in[8];
    const float* A_log     = (const float*)d_in[9];
    const float* D_skip    = (const float*)d_in[10];
    const float* out_proj_w= (const float*)d_in[11];
    const float* fc3_w     = (const float*)d_in[12];
    const float* fc3_b     = (const float*)d_in[13];
    float* out = (float*)d_out;

    float* W = (float*)d_ws;
    float* h     = W + OFF_H;
    float* xz    = W + OFF_XZ;
    float* uc    = W + OFF_UC;
    float* xbc   = W + OFF_XBC;
    float* dtb   = W + OFF_DT;
    float* hloc  = W + OFF_HLOC;
    float* Pp    = W + OFF_PP;
    float* wdt   = W + OFF_WDT;
    float* pooled= W + OFF_POOL;

    // 0. W_dt = dt_proj_w @ x_proj_w[:16,:]   (512,512)
    wdt_kernel<<<(512 * 512) / 256, 256, 0, stream>>>(dt_proj_w, x_proj_w, wdt);
    // 1. h = gelu(x @ fc1_w^T + b)            (32768,1024)x(256,1024) -> (32768,256)
    gemm_bf16<1, false><<<dim3(2, 256), 256, 0, stream>>>(x, IN_SZ, fc1_w, IN_SZ, h, D_MODEL, fc1_b, D_MODEL, IN_SZ);
    // 2. xz = h @ in_proj_w^T                 (32768,256)x(1024,256) -> (32768,1024)
    gemm_bf16<0, false><<<dim3(8, 256), 256, 0, stream>>>(h, D_MODEL, in_proj_w, D_MODEL, xz, 1024, nullptr, 1024, D_MODEL);
    // 3. uc = silu(causal_conv(u) + conv_b)
    conv_silu<<<(BL * D_INNER) / 256, 256, 0, stream>>>(xz, conv_w, conv_b, uc);
    // 4. xbc = uc @ x_proj_w[16:,:]^T         (32768,512)x(32,512) -> (32768,32)
    gemm_bf16<0, true><<<dim3(1, 256), 256, 0, stream>>>(uc, D_INNER, x_proj_w + 16 * D_INNER, D_INNER, xbc, 32, nullptr, 32, D_INNER);
    // 5. dt = softplus(uc @ W_dt^T + dt_b)    (32768,512)x(512,512) -> (32768,512)
    gemm_bf16<2, false><<<dim3(4, 256), 256, 0, stream>>>(uc, D_INNER, wdt, D_INNER, dtb, D_INNER, dt_proj_b, D_INNER, D_INNER);
    // 6-8. chunked selective scan (+ gating fused into pass2, writes over uc)
    scan_pass1<<<dim3(2, NCHUNK, BB), 256, 0, stream>>>(dtb, uc, xbc, A_log, hloc, Pp);
    scan_fixup<<<256, 256, 0, stream>>>(hloc, Pp);
    scan_pass2<<<dim3(2, NCHUNK, BB), 256, 0, stream>>>(dtb, uc, xbc, xz, A_log, D_skip, hloc);
    // 9. h = y @ out_proj_w^T                 (32768,512)x(256,512) -> (32768,256)
    gemm_bf16<0, false><<<dim3(2, 256), 256, 0, stream>>>(uc, D_INNER, out_proj_w, D_INNER, h, D_MODEL, nullptr, D_MODEL, D_INNER);
    // 10-12. mean pool + fc3
    hipMemsetAsync(pooled, 0, BB * D_MODEL * sizeof(float), stream);
    pool_partial<<<dim3(16, BB), 256, 0, stream>>>(h, pooled);
    fc3_kernel<<<BB, 256, 0, stream>>>(pooled, fc3_w, fc3_b, out);
}

// Round 6
// 689.287 us; speedup vs baseline: 2.0576x; 1.2078x over previous
//
#include <hip/hip_runtime.h>
#include <math.h>

// ---------------- problem constants ----------------
#define BB 8
#define LL 4096
#define BL (BB*LL)            // 32768
#define IN_SZ 1024
#define D_MODEL 256
#define D_INNER 512
#define D_STATE 16
#define DT_RANK 16
#define NCLS 2
#define NCHUNK 64
#define CLEN (LL/NCHUNK)      // 64

// ---------------- workspace layout (floats) ----------------
#define OFF_H     ((size_t)0)                       // BL*256
#define OFF_XZ    (OFF_H    + (size_t)BL*D_MODEL)   // BL*1024
#define OFF_UC    (OFF_XZ   + (size_t)BL*1024)      // BL*512
#define OFF_XBC   (OFF_UC   + (size_t)BL*D_INNER)   // BL*32
#define OFF_DT    (OFF_XBC  + (size_t)BL*32)        // BL*512
#define OFF_HLOC  (OFF_DT   + (size_t)BL*D_INNER)   // B*NCHUNK*16*512
#define OFF_PP    (OFF_HLOC + (size_t)BB*NCHUNK*D_STATE*D_INNER)
#define OFF_WDT   (OFF_PP   + (size_t)BB*NCHUNK*D_STATE*D_INNER) // 512*512
#define OFF_POOL  (OFF_WDT  + (size_t)512*512)      // B*256

typedef __bf16 bf16x8 __attribute__((ext_vector_type(8)));
typedef float  f32x4  __attribute__((ext_vector_type(4)));

__device__ __forceinline__ short f2bf(float f) {
    union { float f; unsigned u; } v; v.f = f;
    unsigned r = (v.u + 0x7fffu + ((v.u >> 16) & 1u)) >> 16;
    return (short)r;
}
__device__ __forceinline__ int pack2(float lo, float hi) {
    return (int)((unsigned short)f2bf(lo) | ((unsigned)(unsigned short)f2bf(hi) << 16));
}
// fast exp: native v_exp_f32 (~1 ulp) instead of precise __ocml_exp_f32
__device__ __forceinline__ float fexp(float x) { return __expf(x); }

// =====================================================================
// bf16-MFMA NT GEMM: C[m,n] = sum_k A[m,k]*B[n,k]  (fp32 in/out, fp32 acc)
// BM=BN=128, BK=32, 256 threads = 4 waves (2x2 of 64x64).
// EPI: 0 none, 1 bias+gelu(exact), 2 bias+softplus
// BOUND: bounds-check N (B-staging rows and C columns)
// Requires M%128==0, K%32==0; N%128==0 unless BOUND.
// =====================================================================
template<int EPI, bool BOUND>
__global__ __launch_bounds__(256) void gemm_bf16(
    const float* __restrict__ A, int lda,
    const float* __restrict__ Bw, int ldb,
    float* __restrict__ C, int ldc,
    const float* __restrict__ bias,
    int N, int K)
{
    __shared__ short As[128 * 32];   // [row][k] bf16, 16B-slot swizzled
    __shared__ short Bs[128 * 32];

    const int tid  = threadIdx.x;
    const int m0   = blockIdx.y * 128;
    const int n0   = blockIdx.x * 128;
    const int wave = tid >> 6;
    const int lane = tid & 63;
    const int wr   = wave >> 1;       // wave row (0..1)
    const int wc   = wave & 1;        // wave col (0..1)
    const int r0   = lane & 15;       // row/col within 16-tile
    const int kgf  = lane >> 4;       // k-group of fragment (0..3)

    // staging map: slot s -> row = s>>2, kg = s&3
    const int srow = tid >> 2;        // 0..63
    const int skg  = tid & 3;

    // fragment LDS offsets (in shorts): slot swizzle = kg ^ ((row>>1)&3)
    const int fslot = kgf ^ ((r0 >> 1) & 3);
    const int abase = (wr * 64 + r0) * 32 + fslot * 8;
    const int bbase = (wc * 64 + r0) * 32 + fslot * 8;

    f32x4 acc[4][4];
#pragma unroll
    for (int i = 0; i < 4; i++)
#pragma unroll
        for (int j = 0; j < 4; j++) acc[i][j] = (f32x4){0.f, 0.f, 0.f, 0.f};

    for (int k0 = 0; k0 < K; k0 += 32) {
        float4 av0[2], av1[2], bv0[2], bv1[2];
#pragma unroll
        for (int h = 0; h < 2; h++) {
            int row = srow + h * 64;
            const float* pa = A + (size_t)(m0 + row) * lda + k0 + skg * 8;
            av0[h] = *reinterpret_cast<const float4*>(pa);
            av1[h] = *reinterpret_cast<const float4*>(pa + 4);
            int nn = n0 + row;
            if (!BOUND || nn < N) {
                const float* pb = Bw + (size_t)nn * ldb + k0 + skg * 8;
                bv0[h] = *reinterpret_cast<const float4*>(pb);
                bv1[h] = *reinterpret_cast<const float4*>(pb + 4);
            } else {
                bv0[h] = make_float4(0.f, 0.f, 0.f, 0.f);
                bv1[h] = make_float4(0.f, 0.f, 0.f, 0.f);
            }
        }
        __syncthreads();   // previous tile's frag reads done before overwrite
#pragma unroll
        for (int h = 0; h < 2; h++) {
            int row = srow + h * 64;
            int s = skg ^ ((row >> 1) & 3);
            int4 wa, wb;
            wa.x = pack2(av0[h].x, av0[h].y); wa.y = pack2(av0[h].z, av0[h].w);
            wa.z = pack2(av1[h].x, av1[h].y); wa.w = pack2(av1[h].z, av1[h].w);
            wb.x = pack2(bv0[h].x, bv0[h].y); wb.y = pack2(bv0[h].z, bv0[h].w);
            wb.z = pack2(bv1[h].x, bv1[h].y); wb.w = pack2(bv1[h].z, bv1[h].w);
            *reinterpret_cast<int4*>(&As[row * 32 + s * 8]) = wa;
            *reinterpret_cast<int4*>(&Bs[row * 32 + s * 8]) = wb;
        }
        __syncthreads();

        bf16x8 af[4], bfq[4];
#pragma unroll
        for (int mi = 0; mi < 4; mi++)
            af[mi] = *reinterpret_cast<const bf16x8*>(&As[abase + mi * 16 * 32]);
#pragma unroll
        for (int ni = 0; ni < 4; ni++)
            bfq[ni] = *reinterpret_cast<const bf16x8*>(&Bs[bbase + ni * 16 * 32]);
#pragma unroll
        for (int mi = 0; mi < 4; mi++)
#pragma unroll
            for (int ni = 0; ni < 4; ni++)
                acc[mi][ni] = __builtin_amdgcn_mfma_f32_16x16x32_bf16(
                    af[mi], bfq[ni], acc[mi][ni], 0, 0, 0);
    }

    // epilogue: C/D layout col = lane&15, row = (lane>>4)*4 + reg
#pragma unroll
    for (int mi = 0; mi < 4; mi++) {
#pragma unroll
        for (int ni = 0; ni < 4; ni++) {
            int col = n0 + wc * 64 + ni * 16 + r0;
            if (BOUND && col >= N) continue;
            float bb = (EPI != 0 && bias) ? bias[col] : 0.f;
#pragma unroll
            for (int j = 0; j < 4; j++) {
                int row = m0 + wr * 64 + mi * 16 + kgf * 4 + j;
                float v = acc[mi][ni][j];
                if (EPI == 1) { v += bb; v = 0.5f * v * (1.0f + erff(v * 0.70710678118654752f)); }
                else if (EPI == 2) { v += bb; v = fmaxf(v, 0.f) + log1pf(fexp(-fabsf(v))); }
                C[(size_t)row * ldc + col] = v;
            }
        }
    }
}

// =====================================================================
// W_dt[e][d] = sum_r dt_proj_w[e][r] * x_proj_w[r][d]   (512x512, r<16)
// =====================================================================
__global__ __launch_bounds__(256) void wdt_kernel(
    const float* __restrict__ dtw, const float* __restrict__ xpw,
    float* __restrict__ wdt)
{
    int idx = blockIdx.x * 256 + threadIdx.x;     // 512*512
    int d = idx & 511;
    int e = idx >> 9;
    float s = 0.f;
#pragma unroll
    for (int r = 0; r < 16; r++)
        s = fmaf(dtw[e * 16 + r], xpw[r * 512 + d], s);
    wdt[idx] = s;
}

// =====================================================================
// Depthwise causal conv (width 4) + SiLU.  u = xz[:, :, 0:512]
// =====================================================================
__global__ __launch_bounds__(256) void conv_silu(
    const float* __restrict__ xz, const float* __restrict__ cw,
    const float* __restrict__ cb, float* __restrict__ uc)
{
    int idx = blockIdx.x * 256 + threadIdx.x;
    if (idx >= BL * D_INNER) return;
    int d  = idx & (D_INNER - 1);
    int bl = idx >> 9;
    int l  = bl & (LL - 1);
    const float w0 = cw[d * 4 + 0], w1 = cw[d * 4 + 1];
    const float w2 = cw[d * 4 + 2], w3 = cw[d * 4 + 3];
    const float* up = xz + (size_t)bl * 1024 + d;
    float s = cb[d];
    s = fmaf(up[0], w3, s);
    if (l >= 1) s = fmaf(up[-1024], w2, s);
    if (l >= 2) s = fmaf(up[-2048], w1, s);
    if (l >= 3) s = fmaf(up[-3072], w0, s);
    s = s / (1.f + fexp(-s));
    uc[idx] = s;
}

// =====================================================================
// Selective scan, chunked linear recurrence. xbc layout: [row][32] (B|C)
// pass1: local scan from h=0; decay product computed as exp(A[s]*sum(dt))
// =====================================================================
__global__ __launch_bounds__(256) void scan_pass1(
    const float* __restrict__ dtb, const float* __restrict__ uc,
    const float* __restrict__ xbc, const float* __restrict__ A_log,
    float* __restrict__ hloc, float* __restrict__ Pp)
{
    int d = blockIdx.x * 256 + threadIdx.x;
    int c = blockIdx.y;
    int b = blockIdx.z;
    float Ac[16];
#pragma unroll
    for (int s = 0; s < 16; s++) Ac[s] = -fexp(A_log[d * 16 + s]);
    float h[16];
#pragma unroll
    for (int s = 0; s < 16; s++) h[s] = 0.f;
    float sdt = 0.f;
    int base = b * LL + c * CLEN;
    for (int t = 0; t < CLEN; t++) {
        int row = base + t;
        float dt = dtb[(size_t)row * 512 + d];
        float u  = uc[(size_t)row * 512 + d];
        float du = dt * u;
        sdt += dt;
        const float4* xb = reinterpret_cast<const float4*>(xbc + (size_t)row * 32);
        float Bv[16];
        float4 q;
        q = xb[0]; Bv[0]=q.x; Bv[1]=q.y; Bv[2]=q.z; Bv[3]=q.w;
        q = xb[1]; Bv[4]=q.x; Bv[5]=q.y; Bv[6]=q.z; Bv[7]=q.w;
        q = xb[2]; Bv[8]=q.x; Bv[9]=q.y; Bv[10]=q.z; Bv[11]=q.w;
        q = xb[3]; Bv[12]=q.x; Bv[13]=q.y; Bv[14]=q.z; Bv[15]=q.w;
#pragma unroll
        for (int s = 0; s < 16; s++) {
            float a = fexp(dt * Ac[s]);
            h[s] = fmaf(a, h[s], du * Bv[s]);
        }
    }
    size_t o = ((size_t)(b * NCHUNK + c) * 16) * 512 + d;
#pragma unroll
    for (int s = 0; s < 16; s++) {
        hloc[o + (size_t)s * 512] = h[s];
        Pp[o + (size_t)s * 512] = fexp(Ac[s] * sdt);   // == prod_t exp(dt_t*Ac[s])
    }
}

// fixup: sequential across chunks; rewrite hloc[c] := true initial state of chunk c
__global__ __launch_bounds__(256) void scan_fixup(
    float* __restrict__ hloc, const float* __restrict__ Pp)
{
    int flat = blockIdx.x * 256 + threadIdx.x;   // B*16*512 = 65536
    int d  = flat & 511;
    int bs = flat >> 9;
    int b  = bs >> 4;
    int s  = bs & 15;
    float H = 0.f;
    for (int c = 0; c < NCHUNK; c++) {
        size_t idx = ((size_t)(b * NCHUNK + c) * 16 + s) * 512 + d;
        float hl = hloc[idx];
        float p  = Pp[idx];
        hloc[idx] = H;           // becomes init state for chunk c
        H = fmaf(p, H, hl);
    }
}

// pass2: replay with correct init; emit y_final = (y + u*Dskip)*silu(z), in-place over uc
__global__ __launch_bounds__(256) void scan_pass2(
    const float* __restrict__ dtb, float* __restrict__ uc,
    const float* __restrict__ xbc, const float* __restrict__ xz,
    const float* __restrict__ A_log, const float* __restrict__ Dskip,
    const float* __restrict__ hinit)
{
    int d = blockIdx.x * 256 + threadIdx.x;
    int c = blockIdx.y;
    int b = blockIdx.z;
    float Ac[16];
#pragma unroll
    for (int s = 0; s < 16; s++) Ac[s] = -fexp(A_log[d * 16 + s]);
    float h[16];
    size_t o = ((size_t)(b * NCHUNK + c) * 16) * 512 + d;
#pragma unroll
    for (int s = 0; s < 16; s++) h[s] = hinit[o + (size_t)s * 512];
    const float Dsk = Dskip[d];
    int base = b * LL + c * CLEN;
    for (int t = 0; t < CLEN; t++) {
        int row = base + t;
        float dt = dtb[(size_t)row * 512 + d];
        float u  = uc[(size_t)row * 512 + d];
        float du = dt * u;
        const float4* xb = reinterpret_cast<const float4*>(xbc + (size_t)row * 32);
        float Bv[16], Cv[16];
        float4 q;
        q = xb[0]; Bv[0]=q.x; Bv[1]=q.y; Bv[2]=q.z; Bv[3]=q.w;
        q = xb[1]; Bv[4]=q.x; Bv[5]=q.y; Bv[6]=q.z; Bv[7]=q.w;
        q = xb[2]; Bv[8]=q.x; Bv[9]=q.y; Bv[10]=q.z; Bv[11]=q.w;
        q = xb[3]; Bv[12]=q.x; Bv[13]=q.y; Bv[14]=q.z; Bv[15]=q.w;
        q = xb[4]; Cv[0]=q.x; Cv[1]=q.y; Cv[2]=q.z; Cv[3]=q.w;
        q = xb[5]; Cv[4]=q.x; Cv[5]=q.y; Cv[6]=q.z; Cv[7]=q.w;
        q = xb[6]; Cv[8]=q.x; Cv[9]=q.y; Cv[10]=q.z; Cv[11]=q.w;
        q = xb[7]; Cv[12]=q.x; Cv[13]=q.y; Cv[14]=q.z; Cv[15]=q.w;
        float y = 0.f;
#pragma unroll
        for (int s = 0; s < 16; s++) {
            float a = fexp(dt * Ac[s]);
            h[s] = fmaf(a, h[s], du * Bv[s]);
            y = fmaf(h[s], Cv[s], y);
        }
        float z = xz[(size_t)row * 1024 + 512 + d];
        float sz = z / (1.f + fexp(-z));
        uc[(size_t)row * 512 + d] = (y + u * Dsk) * sz;
    }
}

// =====================================================================
// mean-pool over L (partial, atomics) + final fc3
// =====================================================================
__global__ __launch_bounds__(256) void pool_partial(
    const float* __restrict__ h2, float* __restrict__ pooled)
{
    int t = threadIdx.x;
    int chunk = blockIdx.x;          // 0..15
    int b = blockIdx.y;
    int l0 = chunk * (LL / 16);
    float s = 0.f;
    for (int l = l0; l < l0 + LL / 16; l++)
        s += h2[((size_t)b * LL + l) * D_MODEL + t];
    atomicAdd(&pooled[b * D_MODEL + t], s);
}

__global__ __launch_bounds__(256) void fc3_kernel(
    const float* __restrict__ pooled, const float* __restrict__ w,
    const float* __restrict__ bias, float* __restrict__ out)
{
    __shared__ float red[256];
    int t = threadIdx.x;
    int b = blockIdx.x;
    float p = pooled[b * D_MODEL + t] * (1.0f / LL);
    for (int c = 0; c < NCLS; c++) {
        red[t] = p * w[c * D_MODEL + t];
        __syncthreads();
        for (int off = 128; off > 0; off >>= 1) {
            if (t < off) red[t] += red[t + off];
            __syncthreads();
        }
        if (t == 0) out[b * NCLS + c] = red[0] + bias[c];
        __syncthreads();
    }
}

// =====================================================================
extern "C" void kernel_launch(void* const* d_in, const int* in_sizes, int n_in,
                              void* d_out, int out_size, void* d_ws, size_t ws_size,
                              hipStream_t stream)
{
    const float* x         = (const float*)d_in[0];
    const float* fc1_w     = (const float*)d_in[1];
    const float* fc1_b     = (const float*)d_in[2];
    const float* in_proj_w = (const float*)d_in[3];
    const float* conv_w    = (const float*)d_in[4];
    const float* conv_b    = (const float*)d_in[5];
    const float* x_proj_w  = (const float*)d_in[6];
    const float* dt_proj_w = (const float*)d_in[7];
    const float* dt_proj_b = (const float*)d_in[8];
    const float* A_log     = (const float*)d_in[9];
    const float* D_skip    = (const float*)d_in[10];
    const float* out_proj_w= (const float*)d_in[11];
    const float* fc3_w     = (const float*)d_in[12];
    const float* fc3_b     = (const float*)d_in[13];
    float* out = (float*)d_out;

    float* W = (float*)d_ws;
    float* h     = W + OFF_H;
    float* xz    = W + OFF_XZ;
    float* uc    = W + OFF_UC;
    float* xbc   = W + OFF_XBC;
    float* dtb   = W + OFF_DT;
    float* hloc  = W + OFF_HLOC;
    float* Pp    = W + OFF_PP;
    float* wdt   = W + OFF_WDT;
    float* pooled= W + OFF_POOL;

    // 0. W_dt = dt_proj_w @ x_proj_w[:16,:]   (512,512)
    wdt_kernel<<<(512 * 512) / 256, 256, 0, stream>>>(dt_proj_w, x_proj_w, wdt);
    // 1. h = gelu(x @ fc1_w^T + b)            (32768,1024)x(256,1024) -> (32768,256)
    gemm_bf16<1, false><<<dim3(2, 256), 256, 0, stream>>>(x, IN_SZ, fc1_w, IN_SZ, h, D_MODEL, fc1_b, D_MODEL, IN_SZ);
    // 2. xz = h @ in_proj_w^T                 (32768,256)x(1024,256) -> (32768,1024)
    gemm_bf16<0, false><<<dim3(8, 256), 256, 0, stream>>>(h, D_MODEL, in_proj_w, D_MODEL, xz, 1024, nullptr, 1024, D_MODEL);
    // 3. uc = silu(causal_conv(u) + conv_b)
    conv_silu<<<(BL * D_INNER) / 256, 256, 0, stream>>>(xz, conv_w, conv_b, uc);
    // 4. xbc = uc @ x_proj_w[16:,:]^T         (32768,512)x(32,512) -> (32768,32)
    gemm_bf16<0, true><<<dim3(1, 256), 256, 0, stream>>>(uc, D_INNER, x_proj_w + 16 * D_INNER, D_INNER, xbc, 32, nullptr, 32, D_INNER);
    // 5. dt = softplus(uc @ W_dt^T + dt_b)    (32768,512)x(512,512) -> (32768,512)
    gemm_bf16<2, false><<<dim3(4, 256), 256, 0, stream>>>(uc, D_INNER, wdt, D_INNER, dtb, D_INNER, dt_proj_b, D_INNER, D_INNER);
    // 6-8. chunked selective scan (+ gating fused into pass2, writes over uc)
    scan_pass1<<<dim3(2, NCHUNK, BB), 256, 0, stream>>>(dtb, uc, xbc, A_log, hloc, Pp);
    scan_fixup<<<256, 256, 0, stream>>>(hloc, Pp);
    scan_pass2<<<dim3(2, NCHUNK, BB), 256, 0, stream>>>(dtb, uc, xbc, xz, A_log, D_skip, hloc);
    // 9. h = y @ out_proj_w^T                 (32768,512)x(256,512) -> (32768,256)
    gemm_bf16<0, false><<<dim3(2, 256), 256, 0, stream>>>(uc, D_INNER, out_proj_w, D_INNER, h, D_MODEL, nullptr, D_MODEL, D_INNER);
    // 10-12. mean pool + fc3
    hipMemsetAsync(pooled, 0, BB * D_MODEL * sizeof(float), stream);
    pool_partial<<<dim3(16, BB), 256, 0, stream>>>(h, pooled);
    fc3_kernel<<<BB, 256, 0, stream>>>(pooled, fc3_w, fc3_b, out);
}

// Round 7
// 653.230 us; speedup vs baseline: 2.1712x; 1.0552x over previous
//
#include <hip/hip_runtime.h>
#include <math.h>

// ---------------- problem constants ----------------
#define BB 8
#define LL 4096
#define BL (BB*LL)            // 32768
#define IN_SZ 1024
#define D_MODEL 256
#define D_INNER 512
#define D_STATE 16
#define DT_RANK 16
#define NCLS 2
#define NCHUNK 64
#define CLEN (LL/NCHUNK)      // 64

// ---------------- workspace layout (bytes) ----------------
#define OFF_XB16  ((size_t)0)                          // BL*1024 bf16
#define OFF_HB    (OFF_XB16 + (size_t)BL*1024*2)       // BL*256  bf16
#define OFF_XZB   (OFF_HB   + (size_t)BL*256*2)        // BL*1024 bf16
#define OFF_UCB   (OFF_XZB  + (size_t)BL*1024*2)       // BL*512  bf16
#define OFF_YB    (OFF_UCB  + (size_t)BL*512*2)        // BL*512  bf16
#define OFF_DT    (OFF_YB   + (size_t)BL*512*2)        // BL*512  f32
#define OFF_XBC   (OFF_DT   + (size_t)BL*512*4)        // BL*32   f32
#define OFF_HLOC  (OFF_XBC  + (size_t)BL*32*4)         // 8*64*16*512 f32
#define OFF_PP    (OFF_HLOC + (size_t)BB*NCHUNK*16*512*4)
#define OFF_H2    (OFF_PP   + (size_t)BB*NCHUNK*16*512*4) // BL*256 f32
#define OFF_WCAT  (OFF_H2   + (size_t)BL*256*4)        // 544*512 bf16
#define OFF_FC1WB (OFF_WCAT + (size_t)544*512*2)       // 256*1024 bf16
#define OFF_IPWB  (OFF_FC1WB+ (size_t)256*1024*2)      // 1024*256 bf16
#define OFF_OPWB  (OFF_IPWB + (size_t)1024*256*2)      // 256*512 bf16
#define OFF_POOL  (OFF_OPWB + (size_t)256*512*2)       // 8*256 f32

typedef __bf16 bf16x8 __attribute__((ext_vector_type(8)));
typedef float  f32x4  __attribute__((ext_vector_type(4)));

__device__ __forceinline__ unsigned short f2bf(float f) {
    union { float f; unsigned u; } v; v.f = f;
    unsigned r = (v.u + 0x7fffu + ((v.u >> 16) & 1u)) >> 16;
    return (unsigned short)r;
}
__device__ __forceinline__ int pack2(float lo, float hi) {
    return (int)((unsigned)f2bf(lo) | ((unsigned)f2bf(hi) << 16));
}
__device__ __forceinline__ float b2f(unsigned short u) {
    union { unsigned u; float f; } v; v.u = (unsigned)u << 16; return v.f;
}
__device__ __forceinline__ float fexp(float x) { return __expf(x); }

#define GLOAD16(g, l) __builtin_amdgcn_global_load_lds( \
    (const __attribute__((address_space(1))) void*)(g), \
    (__attribute__((address_space(3))) void*)(l), 16, 0, 0)

// =====================================================================
// bf16 NT GEMM, global_load_lds staging, XOR-swizzled LDS.
// A [M][K] bf16, B [N][K] bf16, C row-major.
// BM=BN=128, BK=64, 256 threads = 4 waves (2x2 of 64x64 per wave).
// EPI: 0 none, 1 bias+gelu->OUT, 2 bias+softplus->OUT, 3 dt|bc split
// OUTBF: 1 -> ushort(bf16) C, 0 -> float C  (EPI3 writes both fp32)
// BOUND: clamp B-rows / mask C-cols to N.
// =====================================================================
template<int EPI, bool BOUND, int OUTBF>
__global__ __launch_bounds__(256) void gemm_bf16(
    const unsigned short* __restrict__ A, int lda,
    const unsigned short* __restrict__ Bw, int ldb,
    void* __restrict__ Cout, int ldc,
    float* __restrict__ C2,            // EPI3: xbc
    const float* __restrict__ bias,
    int N, int K)
{
    __shared__ unsigned short smem[2 * 128 * 64];   // As | Bs, 16KB each

    const int tid  = threadIdx.x;
    const int m0   = blockIdx.y * 128;
    const int n0   = blockIdx.x * 128;
    const int wv   = tid >> 6;
    const int lane = tid & 63;
    const int wr   = wv >> 1;
    const int wc   = wv & 1;
    const int r0   = lane & 15;
    const int kgf  = lane >> 4;

    f32x4 acc[4][4];
#pragma unroll
    for (int i = 0; i < 4; i++)
#pragma unroll
        for (int j = 0; j < 4; j++) acc[i][j] = (f32x4){0.f, 0.f, 0.f, 0.f};

    for (int k0 = 0; k0 < K; k0 += 64) {
        __syncthreads();                // frag reads of previous tile complete
#pragma unroll
        for (int r = 0; r < 4; r++) {
            int q   = r * 4 + wv;
            int row = q * 8 + (lane >> 3);
            int c   = (lane & 7) ^ (row & 7);        // pre-swizzled source chunk
            const unsigned short* ga = A + (size_t)(m0 + row) * lda + k0 + c * 8;
            GLOAD16(ga, &smem[q * 512]);
            int nn = n0 + row;
            if (BOUND && nn > N - 1) nn = N - 1;     // clamped dup; masked at C
            const unsigned short* gb = Bw + (size_t)nn * ldb + k0 + c * 8;
            GLOAD16(gb, &smem[8192 + q * 512]);
        }
        __syncthreads();                // vmcnt(0) drained by compiler

#pragma unroll
        for (int kk = 0; kk < 2; kk++) {
            bf16x8 af[4], bfq[4];
            const int sl = ((kk << 2) + kgf) ^ (r0 & 7);
#pragma unroll
            for (int mi = 0; mi < 4; mi++)
                af[mi] = *reinterpret_cast<const bf16x8*>(
                    &smem[(wr * 64 + mi * 16 + r0) * 64 + sl * 8]);
#pragma unroll
            for (int ni = 0; ni < 4; ni++)
                bfq[ni] = *reinterpret_cast<const bf16x8*>(
                    &smem[8192 + (wc * 64 + ni * 16 + r0) * 64 + sl * 8]);
#pragma unroll
            for (int mi = 0; mi < 4; mi++)
#pragma unroll
                for (int ni = 0; ni < 4; ni++)
                    acc[mi][ni] = __builtin_amdgcn_mfma_f32_16x16x32_bf16(
                        af[mi], bfq[ni], acc[mi][ni], 0, 0, 0);
        }
    }

    // epilogue: C/D layout col = lane&15, row = (lane>>4)*4 + reg
#pragma unroll
    for (int mi = 0; mi < 4; mi++) {
#pragma unroll
        for (int ni = 0; ni < 4; ni++) {
            int col = n0 + wc * 64 + ni * 16 + r0;
            if (BOUND && col >= N) continue;
#pragma unroll
            for (int j = 0; j < 4; j++) {
                int row = m0 + wr * 64 + mi * 16 + kgf * 4 + j;
                float v = acc[mi][ni][j];
                if (EPI == 1) {
                    v += bias[col];
                    v = 0.5f * v * (1.0f + erff(v * 0.70710678118654752f));
                } else if (EPI == 2) {
                    v += bias[col];
                    v = fmaxf(v, 0.f) + log1pf(fexp(-fabsf(v)));
                }
                if (EPI == 3) {
                    if (col < 512) {
                        v += bias[col];
                        v = fmaxf(v, 0.f) + log1pf(fexp(-fabsf(v)));
                        ((float*)Cout)[(size_t)row * 512 + col] = v;
                    } else {
                        C2[(size_t)row * 32 + (col - 512)] = v;
                    }
                } else if (OUTBF) {
                    ((unsigned short*)Cout)[(size_t)row * ldc + col] = f2bf(v);
                } else {
                    ((float*)Cout)[(size_t)row * ldc + col] = v;
                }
            }
        }
    }
}

// =====================================================================
// fp32 -> bf16 bulk convert (n8 = n/8 threads-worth, n % 2048 == 0)
// =====================================================================
__global__ __launch_bounds__(256) void f2b_kernel(
    const float* __restrict__ src, unsigned short* __restrict__ dst, int n8)
{
    int i = blockIdx.x * 256 + threadIdx.x;
    if (i >= n8) return;
    const float4* s = reinterpret_cast<const float4*>(src) + (size_t)i * 2;
    float4 a = s[0], b = s[1];
    int4 o;
    o.x = pack2(a.x, a.y); o.y = pack2(a.z, a.w);
    o.z = pack2(b.x, b.y); o.w = pack2(b.z, b.w);
    reinterpret_cast<int4*>(dst)[i] = o;
}

// =====================================================================
// wcat[e][d], e<512: (dt_proj_w @ x_proj_w[:16])[e][d] ; e in [512,544):
// x_proj_w[16 + e-512][d].  Output bf16.
// =====================================================================
__global__ __launch_bounds__(256) void wcat_kernel(
    const float* __restrict__ dtw, const float* __restrict__ xpw,
    unsigned short* __restrict__ wcat)
{
    int idx = blockIdx.x * 256 + threadIdx.x;     // 544*512
    int d = idx & 511;
    int e = idx >> 9;
    float s;
    if (e < 512) {
        s = 0.f;
#pragma unroll
        for (int r = 0; r < 16; r++)
            s = fmaf(dtw[e * 16 + r], xpw[r * 512 + d], s);
    } else {
        s = xpw[(16 + e - 512) * 512 + d];
    }
    wcat[idx] = f2bf(s);
}

// =====================================================================
// Depthwise causal conv (width 4) + SiLU; bf16 in (u-half of xz), bf16 out
// =====================================================================
__global__ __launch_bounds__(256) void conv_silu(
    const unsigned short* __restrict__ xzb, const float* __restrict__ cw,
    const float* __restrict__ cb, unsigned short* __restrict__ ucb)
{
    int idx = blockIdx.x * 256 + threadIdx.x;
    if (idx >= BL * D_INNER) return;
    int d  = idx & (D_INNER - 1);
    int bl = idx >> 9;
    int l  = bl & (LL - 1);
    const float w0 = cw[d * 4 + 0], w1 = cw[d * 4 + 1];
    const float w2 = cw[d * 4 + 2], w3 = cw[d * 4 + 3];
    const unsigned short* up = xzb + (size_t)bl * 1024 + d;
    float s = cb[d];
    s = fmaf(b2f(up[0]), w3, s);
    if (l >= 1) s = fmaf(b2f(up[-1024]), w2, s);
    if (l >= 2) s = fmaf(b2f(up[-2048]), w1, s);
    if (l >= 3) s = fmaf(b2f(up[-3072]), w0, s);
    s = s / (1.f + fexp(-s));
    ucb[idx] = f2bf(s);
}

// =====================================================================
// Selective scan, chunked linear recurrence. xbc fp32 [row][32] (B|C)
// =====================================================================
__global__ __launch_bounds__(256) void scan_pass1(
    const float* __restrict__ dtb, const unsigned short* __restrict__ ucb,
    const float* __restrict__ xbc, const float* __restrict__ A_log,
    float* __restrict__ hloc, float* __restrict__ Pp)
{
    int d = blockIdx.x * 256 + threadIdx.x;
    int c = blockIdx.y;
    int b = blockIdx.z;
    float Ac[16];
#pragma unroll
    for (int s = 0; s < 16; s++) Ac[s] = -fexp(A_log[d * 16 + s]);
    float h[16];
#pragma unroll
    for (int s = 0; s < 16; s++) h[s] = 0.f;
    float sdt = 0.f;
    int base = b * LL + c * CLEN;
    for (int t = 0; t < CLEN; t++) {
        int row = base + t;
        float dt = dtb[(size_t)row * 512 + d];
        float u  = b2f(ucb[(size_t)row * 512 + d]);
        float du = dt * u;
        sdt += dt;
        const float4* xb = reinterpret_cast<const float4*>(xbc + (size_t)row * 32);
        float Bv[16];
        float4 q;
        q = xb[0]; Bv[0]=q.x; Bv[1]=q.y; Bv[2]=q.z; Bv[3]=q.w;
        q = xb[1]; Bv[4]=q.x; Bv[5]=q.y; Bv[6]=q.z; Bv[7]=q.w;
        q = xb[2]; Bv[8]=q.x; Bv[9]=q.y; Bv[10]=q.z; Bv[11]=q.w;
        q = xb[3]; Bv[12]=q.x; Bv[13]=q.y; Bv[14]=q.z; Bv[15]=q.w;
#pragma unroll
        for (int s = 0; s < 16; s++) {
            float a = fexp(dt * Ac[s]);
            h[s] = fmaf(a, h[s], du * Bv[s]);
        }
    }
    size_t o = ((size_t)(b * NCHUNK + c) * 16) * 512 + d;
#pragma unroll
    for (int s = 0; s < 16; s++) {
        hloc[o + (size_t)s * 512] = h[s];
        Pp[o + (size_t)s * 512] = fexp(Ac[s] * sdt);   // == prod_t exp(dt_t*Ac[s])
    }
}

__global__ __launch_bounds__(256) void scan_fixup(
    float* __restrict__ hloc, const float* __restrict__ Pp)
{
    int flat = blockIdx.x * 256 + threadIdx.x;   // B*16*512 = 65536
    int d  = flat & 511;
    int bs = flat >> 9;
    int b  = bs >> 4;
    int s  = bs & 15;
    float H = 0.f;
    for (int c = 0; c < NCHUNK; c++) {
        size_t idx = ((size_t)(b * NCHUNK + c) * 16 + s) * 512 + d;
        float hl = hloc[idx];
        float p  = Pp[idx];
        hloc[idx] = H;           // becomes init state for chunk c
        H = fmaf(p, H, hl);
    }
}

// pass2: replay with correct init; y=(scan+u*Dsk)*silu(z) -> yb (bf16)
__global__ __launch_bounds__(256) void scan_pass2(
    const float* __restrict__ dtb, const unsigned short* __restrict__ ucb,
    const float* __restrict__ xbc, const unsigned short* __restrict__ xzb,
    const float* __restrict__ A_log, const float* __restrict__ Dskip,
    const float* __restrict__ hinit, unsigned short* __restrict__ yb)
{
    int d = blockIdx.x * 256 + threadIdx.x;
    int c = blockIdx.y;
    int b = blockIdx.z;
    float Ac[16];
#pragma unroll
    for (int s = 0; s < 16; s++) Ac[s] = -fexp(A_log[d * 16 + s]);
    float h[16];
    size_t o = ((size_t)(b * NCHUNK + c) * 16) * 512 + d;
#pragma unroll
    for (int s = 0; s < 16; s++) h[s] = hinit[o + (size_t)s * 512];
    const float Dsk = Dskip[d];
    int base = b * LL + c * CLEN;
    for (int t = 0; t < CLEN; t++) {
        int row = base + t;
        float dt = dtb[(size_t)row * 512 + d];
        float u  = b2f(ucb[(size_t)row * 512 + d]);
        float du = dt * u;
        const float4* xb = reinterpret_cast<const float4*>(xbc + (size_t)row * 32);
        float Bv[16], Cv[16];
        float4 q;
        q = xb[0]; Bv[0]=q.x; Bv[1]=q.y; Bv[2]=q.z; Bv[3]=q.w;
        q = xb[1]; Bv[4]=q.x; Bv[5]=q.y; Bv[6]=q.z; Bv[7]=q.w;
        q = xb[2]; Bv[8]=q.x; Bv[9]=q.y; Bv[10]=q.z; Bv[11]=q.w;
        q = xb[3]; Bv[12]=q.x; Bv[13]=q.y; Bv[14]=q.z; Bv[15]=q.w;
        q = xb[4]; Cv[0]=q.x; Cv[1]=q.y; Cv[2]=q.z; Cv[3]=q.w;
        q = xb[5]; Cv[4]=q.x; Cv[5]=q.y; Cv[6]=q.z; Cv[7]=q.w;
        q = xb[6]; Cv[8]=q.x; Cv[9]=q.y; Cv[10]=q.z; Cv[11]=q.w;
        q = xb[7]; Cv[12]=q.x; Cv[13]=q.y; Cv[14]=q.z; Cv[15]=q.w;
        float y = 0.f;
#pragma unroll
        for (int s = 0; s < 16; s++) {
            float a = fexp(dt * Ac[s]);
            h[s] = fmaf(a, h[s], du * Bv[s]);
            y = fmaf(h[s], Cv[s], y);
        }
        float z = b2f(xzb[(size_t)row * 1024 + 512 + d]);
        float sz = z / (1.f + fexp(-z));
        yb[(size_t)row * 512 + d] = f2bf((y + u * Dsk) * sz);
    }
}

// =====================================================================
// mean-pool over L (partial, atomics) + final fc3
// =====================================================================
__global__ __launch_bounds__(256) void pool_partial(
    const float* __restrict__ h2, float* __restrict__ pooled)
{
    int t = threadIdx.x;
    int chunk = blockIdx.x;          // 0..15
    int b = blockIdx.y;
    int l0 = chunk * (LL / 16);
    float s = 0.f;
    for (int l = l0; l < l0 + LL / 16; l++)
        s += h2[((size_t)b * LL + l) * D_MODEL + t];
    atomicAdd(&pooled[b * D_MODEL + t], s);
}

__global__ __launch_bounds__(256) void fc3_kernel(
    const float* __restrict__ pooled, const float* __restrict__ w,
    const float* __restrict__ bias, float* __restrict__ out)
{
    __shared__ float red[256];
    int t = threadIdx.x;
    int b = blockIdx.x;
    float p = pooled[b * D_MODEL + t] * (1.0f / LL);
    for (int c = 0; c < NCLS; c++) {
        red[t] = p * w[c * D_MODEL + t];
        __syncthreads();
        for (int off = 128; off > 0; off >>= 1) {
            if (t < off) red[t] += red[t + off];
            __syncthreads();
        }
        if (t == 0) out[b * NCLS + c] = red[0] + bias[c];
        __syncthreads();
    }
}

// =====================================================================
extern "C" void kernel_launch(void* const* d_in, const int* in_sizes, int n_in,
                              void* d_out, int out_size, void* d_ws, size_t ws_size,
                              hipStream_t stream)
{
    const float* x         = (const float*)d_in[0];
    const float* fc1_w     = (const float*)d_in[1];
    const float* fc1_b     = (const float*)d_in[2];
    const float* in_proj_w = (const float*)d_in[3];
    const float* conv_w    = (const float*)d_in[4];
    const float* conv_b    = (const float*)d_in[5];
    const float* x_proj_w  = (const float*)d_in[6];
    const float* dt_proj_w = (const float*)d_in[7];
    const float* dt_proj_b = (const float*)d_in[8];
    const float* A_log     = (const float*)d_in[9];
    const float* D_skip    = (const float*)d_in[10];
    const float* out_proj_w= (const float*)d_in[11];
    const float* fc3_w     = (const float*)d_in[12];
    const float* fc3_b     = (const float*)d_in[13];
    float* out = (float*)d_out;

    char* WS = (char*)d_ws;
    unsigned short* xb16  = (unsigned short*)(WS + OFF_XB16);
    unsigned short* hb    = (unsigned short*)(WS + OFF_HB);
    unsigned short* xzb   = (unsigned short*)(WS + OFF_XZB);
    unsigned short* ucb   = (unsigned short*)(WS + OFF_UCB);
    unsigned short* yb    = (unsigned short*)(WS + OFF_YB);
    float*          dtb   = (float*)(WS + OFF_DT);
    float*          xbc   = (float*)(WS + OFF_XBC);
    float*          hloc  = (float*)(WS + OFF_HLOC);
    float*          Pp    = (float*)(WS + OFF_PP);
    float*          h2    = (float*)(WS + OFF_H2);
    unsigned short* wcat  = (unsigned short*)(WS + OFF_WCAT);
    unsigned short* fc1wb = (unsigned short*)(WS + OFF_FC1WB);
    unsigned short* ipwb  = (unsigned short*)(WS + OFF_IPWB);
    unsigned short* opwb  = (unsigned short*)(WS + OFF_OPWB);
    float*          pooled= (float*)(WS + OFF_POOL);

    // 0. dtype converts (once per call)
    f2b_kernel<<<(BL * 1024 / 8) / 256, 256, 0, stream>>>(x, xb16, BL * 1024 / 8);
    f2b_kernel<<<(256 * 1024 / 8) / 256, 256, 0, stream>>>(fc1_w, fc1wb, 256 * 1024 / 8);
    f2b_kernel<<<(1024 * 256 / 8) / 256, 256, 0, stream>>>(in_proj_w, ipwb, 1024 * 256 / 8);
    f2b_kernel<<<(256 * 512 / 8) / 256, 256, 0, stream>>>(out_proj_w, opwb, 256 * 512 / 8);
    wcat_kernel<<<(544 * 512) / 256, 256, 0, stream>>>(dt_proj_w, x_proj_w, wcat);

    // 1. h = gelu(x @ fc1_w^T + b)            -> bf16 (32768,256)
    gemm_bf16<1, false, 1><<<dim3(2, 256), 256, 0, stream>>>(
        xb16, IN_SZ, fc1wb, IN_SZ, hb, D_MODEL, nullptr, fc1_b, D_MODEL, IN_SZ);
    // 2. xz = h @ in_proj_w^T                 -> bf16 (32768,1024)
    gemm_bf16<0, false, 1><<<dim3(8, 256), 256, 0, stream>>>(
        hb, D_MODEL, ipwb, D_MODEL, xzb, 1024, nullptr, nullptr, 1024, D_MODEL);
    // 3. uc = silu(causal_conv(u) + conv_b)   -> bf16
    conv_silu<<<(BL * D_INNER) / 256, 256, 0, stream>>>(xzb, conv_w, conv_b, ucb);
    // 4+5 fused: [dt|bc] = uc @ wcat^T ; dt->softplus->dtb(f32), bc->xbc(f32)
    gemm_bf16<3, true, 0><<<dim3(5, 256), 256, 0, stream>>>(
        ucb, D_INNER, wcat, D_INNER, dtb, 512, xbc, dt_proj_b, 544, D_INNER);
    // 6-8. chunked selective scan (+ gating fused into pass2 -> yb bf16)
    scan_pass1<<<dim3(2, NCHUNK, BB), 256, 0, stream>>>(dtb, ucb, xbc, A_log, hloc, Pp);
    scan_fixup<<<256, 256, 0, stream>>>(hloc, Pp);
    scan_pass2<<<dim3(2, NCHUNK, BB), 256, 0, stream>>>(dtb, ucb, xbc, xzb, A_log, D_skip, hloc, yb);
    // 9. h2 = y @ out_proj_w^T                -> f32 (32768,256)
    gemm_bf16<0, false, 0><<<dim3(2, 256), 256, 0, stream>>>(
        yb, D_INNER, opwb, D_INNER, h2, D_MODEL, nullptr, nullptr, D_MODEL, D_INNER);
    // 10-12. mean pool + fc3
    hipMemsetAsync(pooled, 0, BB * D_MODEL * sizeof(float), stream);
    pool_partial<<<dim3(16, BB), 256, 0, stream>>>(h2, pooled);
    fc3_kernel<<<BB, 256, 0, stream>>>(pooled, fc3_w, fc3_b, out);
}

// Round 8
// 585.682 us; speedup vs baseline: 2.4216x; 1.1153x over previous
//
#include <hip/hip_runtime.h>
#include <math.h>

// ---------------- problem constants ----------------
#define BB 8
#define LL 4096
#define BL (BB*LL)            // 32768
#define IN_SZ 1024
#define D_MODEL 256
#define D_INNER 512
#define D_STATE 16
#define DT_RANK 16
#define NCLS 2
#define NCHUNK 64
#define CLEN (LL/NCHUNK)      // 64

// ---------------- workspace layout (bytes) ----------------
#define OFF_XB16  ((size_t)0)                          // BL*1024 bf16
#define OFF_HB    (OFF_XB16 + (size_t)BL*1024*2)       // BL*256  bf16
#define OFF_XZB   (OFF_HB   + (size_t)BL*256*2)        // BL*1024 bf16
#define OFF_UCB   (OFF_XZB  + (size_t)BL*1024*2)       // BL*512  bf16
#define OFF_YB    (OFF_UCB  + (size_t)BL*512*2)        // BL*512  bf16
#define OFF_DT    (OFF_YB   + (size_t)BL*512*2)        // BL*512  f32
#define OFF_XBC   (OFF_DT   + (size_t)BL*512*4)        // BL*32   f32
#define OFF_HLOC  (OFF_XBC  + (size_t)BL*32*4)         // 8*64*16*512 f32
#define OFF_PP    (OFF_HLOC + (size_t)BB*NCHUNK*16*512*4)
#define OFF_H2    (OFF_PP   + (size_t)BB*NCHUNK*16*512*4) // BL*256 f32
#define OFF_WCAT  (OFF_H2   + (size_t)BL*256*4)        // 544*512 bf16
#define OFF_FC1WB (OFF_WCAT + (size_t)544*512*2)       // 256*1024 bf16
#define OFF_IPWB  (OFF_FC1WB+ (size_t)256*1024*2)      // 1024*256 bf16
#define OFF_OPWB  (OFF_IPWB + (size_t)1024*256*2)      // 256*512 bf16
#define OFF_POOL  (OFF_OPWB + (size_t)256*512*2)       // 8*256 f32

typedef __bf16 bf16x8 __attribute__((ext_vector_type(8)));
typedef float  f32x4  __attribute__((ext_vector_type(4)));

__device__ __forceinline__ unsigned short f2bf(float f) {
    union { float f; unsigned u; } v; v.f = f;
    unsigned r = (v.u + 0x7fffu + ((v.u >> 16) & 1u)) >> 16;
    return (unsigned short)r;
}
__device__ __forceinline__ int pack2(float lo, float hi) {
    return (int)((unsigned)f2bf(lo) | ((unsigned)f2bf(hi) << 16));
}
__device__ __forceinline__ float b2f(unsigned short u) {
    union { unsigned u; float f; } v; v.u = (unsigned)u << 16; return v.f;
}
__device__ __forceinline__ float fexp(float x) { return __expf(x); }

#define GLOAD16(g, l) __builtin_amdgcn_global_load_lds( \
    (const __attribute__((address_space(1))) void*)(g), \
    (__attribute__((address_space(3))) void*)(l), 16, 0, 0)

// =====================================================================
// bf16 NT GEMM, 2-phase double-buffered global_load_lds pipeline.
// A [M][K] bf16, B [N][K] bf16. BM=BN=128, BK=64, 256 thr = 4 waves.
// blockIdx.x = M-tile (fast index -> each A-tile fetched once),
// blockIdx.y = N-tile (shared B weight panel, L2-cached per XCD).
// EPI: 0 none, 1 bias+gelu, 2 bias+softplus, 3 dt|bc split (fp32 out)
// OUTBF: 1 -> bf16 C, 0 -> fp32 C. BOUND: clamp B rows / mask C cols.
// =====================================================================
template<int EPI, bool BOUND, int OUTBF>
__global__ __launch_bounds__(256) void gemm_bf16(
    const unsigned short* __restrict__ A, int lda,
    const unsigned short* __restrict__ Bw, int ldb,
    void* __restrict__ Cout, int ldc,
    float* __restrict__ C2,            // EPI3: xbc
    const float* __restrict__ bias,
    int N, int K)
{
    __shared__ unsigned short smem[2][16384];   // [buf][A(8192) | B(8192)]

    const int tid  = threadIdx.x;
    const int m0   = blockIdx.x * 128;
    const int n0   = blockIdx.y * 128;
    const int wv   = tid >> 6;
    const int lane = tid & 63;
    const int wr   = wv >> 1;
    const int wc   = wv & 1;
    const int r0   = lane & 15;
    const int kgf  = lane >> 4;

    // staging geometry (loop-invariant): q in {wv,4+wv,8+wv,12+wv}
    const unsigned short* Ag[4];
    const unsigned short* Bg[4];
    int ldso[4];
#pragma unroll
    for (int r = 0; r < 4; r++) {
        int q   = r * 4 + wv;
        int row = q * 8 + (lane >> 3);
        int c   = (lane & 7) ^ (row & 7);        // pre-swizzled source chunk
        Ag[r] = A + (size_t)(m0 + row) * lda + c * 8;
        int nn = n0 + row;
        if (BOUND && nn > N - 1) nn = N - 1;     // clamped dup; masked at C
        Bg[r] = Bw + (size_t)nn * ldb + c * 8;
        ldso[r] = q * 512;
    }

    f32x4 acc[4][4];
#pragma unroll
    for (int i = 0; i < 4; i++)
#pragma unroll
        for (int j = 0; j < 4; j++) acc[i][j] = (f32x4){0.f, 0.f, 0.f, 0.f};

    // prologue: stage tile 0 into buf 0
#pragma unroll
    for (int r = 0; r < 4; r++) {
        GLOAD16(Ag[r], &smem[0][ldso[r]]);
        GLOAD16(Bg[r], &smem[0][8192 + ldso[r]]);
    }
    __syncthreads();                     // compiler drains vmcnt(0) here

    const int nk = K >> 6;
    int cur = 0;
    for (int t = 0; t < nk; ++t) {
        if (t + 1 < nk) {                // issue next-tile loads FIRST
            int koff = (t + 1) << 6;
#pragma unroll
            for (int r = 0; r < 4; r++) {
                GLOAD16(Ag[r] + koff, &smem[cur ^ 1][ldso[r]]);
                GLOAD16(Bg[r] + koff, &smem[cur ^ 1][8192 + ldso[r]]);
            }
        }
        // compute current buffer (HBM latency of the staged loads hides here)
#pragma unroll
        for (int kk = 0; kk < 2; kk++) {
            bf16x8 af[4], bfq[4];
            const int sl = ((kk << 2) + kgf) ^ (r0 & 7);
#pragma unroll
            for (int mi = 0; mi < 4; mi++)
                af[mi] = *reinterpret_cast<const bf16x8*>(
                    &smem[cur][(wr * 64 + mi * 16 + r0) * 64 + sl * 8]);
#pragma unroll
            for (int ni = 0; ni < 4; ni++)
                bfq[ni] = *reinterpret_cast<const bf16x8*>(
                    &smem[cur][8192 + (wc * 64 + ni * 16 + r0) * 64 + sl * 8]);
#pragma unroll
            for (int mi = 0; mi < 4; mi++)
#pragma unroll
                for (int ni = 0; ni < 4; ni++)
                    acc[mi][ni] = __builtin_amdgcn_mfma_f32_16x16x32_bf16(
                        af[mi], bfq[ni], acc[mi][ni], 0, 0, 0);
        }
        __syncthreads();                 // drain staged loads; all reads of cur done
        cur ^= 1;
    }

    // epilogue: C/D layout col = lane&15, row = (lane>>4)*4 + reg
#pragma unroll
    for (int mi = 0; mi < 4; mi++) {
#pragma unroll
        for (int ni = 0; ni < 4; ni++) {
            int col = n0 + wc * 64 + ni * 16 + r0;
            if (BOUND && col >= N) continue;
#pragma unroll
            for (int j = 0; j < 4; j++) {
                int row = m0 + wr * 64 + mi * 16 + kgf * 4 + j;
                float v = acc[mi][ni][j];
                if (EPI == 1) {
                    v += bias[col];
                    v = 0.5f * v * (1.0f + erff(v * 0.70710678118654752f));
                } else if (EPI == 2) {
                    v += bias[col];
                    v = fmaxf(v, 0.f) + __logf(1.f + fexp(-fabsf(v)));
                }
                if (EPI == 3) {
                    if (col < 512) {
                        v += bias[col];
                        v = fmaxf(v, 0.f) + __logf(1.f + fexp(-fabsf(v)));
                        ((float*)Cout)[(size_t)row * 512 + col] = v;
                    } else {
                        C2[(size_t)row * 32 + (col - 512)] = v;
                    }
                } else if (OUTBF) {
                    ((unsigned short*)Cout)[(size_t)row * ldc + col] = f2bf(v);
                } else {
                    ((float*)Cout)[(size_t)row * ldc + col] = v;
                }
            }
        }
    }
}

// =====================================================================
// fp32 -> bf16 bulk convert
// =====================================================================
__global__ __launch_bounds__(256) void f2b_kernel(
    const float* __restrict__ src, unsigned short* __restrict__ dst, int n8)
{
    int i = blockIdx.x * 256 + threadIdx.x;
    if (i >= n8) return;
    const float4* s = reinterpret_cast<const float4*>(src) + (size_t)i * 2;
    float4 a = s[0], b = s[1];
    int4 o;
    o.x = pack2(a.x, a.y); o.y = pack2(a.z, a.w);
    o.z = pack2(b.x, b.y); o.w = pack2(b.z, b.w);
    reinterpret_cast<int4*>(dst)[i] = o;
}

// =====================================================================
// wcat[e][d], e<512: (dt_proj_w @ x_proj_w[:16])[e][d] ; e in [512,544):
// x_proj_w[16 + e-512][d].  Output bf16.
// =====================================================================
__global__ __launch_bounds__(256) void wcat_kernel(
    const float* __restrict__ dtw, const float* __restrict__ xpw,
    unsigned short* __restrict__ wcat)
{
    int idx = blockIdx.x * 256 + threadIdx.x;     // 544*512
    int d = idx & 511;
    int e = idx >> 9;
    float s;
    if (e < 512) {
        s = 0.f;
#pragma unroll
        for (int r = 0; r < 16; r++)
            s = fmaf(dtw[e * 16 + r], xpw[r * 512 + d], s);
    } else {
        s = xpw[(16 + e - 512) * 512 + d];
    }
    wcat[idx] = f2bf(s);
}

// =====================================================================
// Depthwise causal conv (width 4) + SiLU; bf16 in (u-half of xz), bf16 out
// =====================================================================
__global__ __launch_bounds__(256) void conv_silu(
    const unsigned short* __restrict__ xzb, const float* __restrict__ cw,
    const float* __restrict__ cb, unsigned short* __restrict__ ucb)
{
    int idx = blockIdx.x * 256 + threadIdx.x;
    if (idx >= BL * D_INNER) return;
    int d  = idx & (D_INNER - 1);
    int bl = idx >> 9;
    int l  = bl & (LL - 1);
    const float w0 = cw[d * 4 + 0], w1 = cw[d * 4 + 1];
    const float w2 = cw[d * 4 + 2], w3 = cw[d * 4 + 3];
    const unsigned short* up = xzb + (size_t)bl * 1024 + d;
    float s = cb[d];
    s = fmaf(b2f(up[0]), w3, s);
    if (l >= 1) s = fmaf(b2f(up[-1024]), w2, s);
    if (l >= 2) s = fmaf(b2f(up[-2048]), w1, s);
    if (l >= 3) s = fmaf(b2f(up[-3072]), w0, s);
    s = s / (1.f + fexp(-s));
    ucb[idx] = f2bf(s);
}

// =====================================================================
// Selective scan, chunked linear recurrence. xbc fp32 [row][32] (B|C)
// =====================================================================
__global__ __launch_bounds__(256) void scan_pass1(
    const float* __restrict__ dtb, const unsigned short* __restrict__ ucb,
    const float* __restrict__ xbc, const float* __restrict__ A_log,
    float* __restrict__ hloc, float* __restrict__ Pp)
{
    int d = blockIdx.x * 256 + threadIdx.x;
    int c = blockIdx.y;
    int b = blockIdx.z;
    float Ac[16];
#pragma unroll
    for (int s = 0; s < 16; s++) Ac[s] = -fexp(A_log[d * 16 + s]);
    float h[16];
#pragma unroll
    for (int s = 0; s < 16; s++) h[s] = 0.f;
    float sdt = 0.f;
    int base = b * LL + c * CLEN;
    for (int t = 0; t < CLEN; t++) {
        int row = base + t;
        float dt = dtb[(size_t)row * 512 + d];
        float u  = b2f(ucb[(size_t)row * 512 + d]);
        float du = dt * u;
        sdt += dt;
        const float4* xb = reinterpret_cast<const float4*>(xbc + (size_t)row * 32);
        float Bv[16];
        float4 q;
        q = xb[0]; Bv[0]=q.x; Bv[1]=q.y; Bv[2]=q.z; Bv[3]=q.w;
        q = xb[1]; Bv[4]=q.x; Bv[5]=q.y; Bv[6]=q.z; Bv[7]=q.w;
        q = xb[2]; Bv[8]=q.x; Bv[9]=q.y; Bv[10]=q.z; Bv[11]=q.w;
        q = xb[3]; Bv[12]=q.x; Bv[13]=q.y; Bv[14]=q.z; Bv[15]=q.w;
#pragma unroll
        for (int s = 0; s < 16; s++) {
            float a = fexp(dt * Ac[s]);
            h[s] = fmaf(a, h[s], du * Bv[s]);
        }
    }
    size_t o = ((size_t)(b * NCHUNK + c) * 16) * 512 + d;
#pragma unroll
    for (int s = 0; s < 16; s++) {
        hloc[o + (size_t)s * 512] = h[s];
        Pp[o + (size_t)s * 512] = fexp(Ac[s] * sdt);   // == prod_t exp(dt_t*Ac[s])
    }
}

__global__ __launch_bounds__(256) void scan_fixup(
    float* __restrict__ hloc, const float* __restrict__ Pp)
{
    int flat = blockIdx.x * 256 + threadIdx.x;   // B*16*512 = 65536
    int d  = flat & 511;
    int bs = flat >> 9;
    int b  = bs >> 4;
    int s  = bs & 15;
    float H = 0.f;
    for (int c = 0; c < NCHUNK; c++) {
        size_t idx = ((size_t)(b * NCHUNK + c) * 16 + s) * 512 + d;
        float hl = hloc[idx];
        float p  = Pp[idx];
        hloc[idx] = H;           // becomes init state for chunk c
        H = fmaf(p, H, hl);
    }
}

// pass2: replay with correct init; y=(scan+u*Dsk)*silu(z) -> yb (bf16)
__global__ __launch_bounds__(256) void scan_pass2(
    const float* __restrict__ dtb, const unsigned short* __restrict__ ucb,
    const float* __restrict__ xbc, const unsigned short* __restrict__ xzb,
    const float* __restrict__ A_log, const float* __restrict__ Dskip,
    const float* __restrict__ hinit, unsigned short* __restrict__ yb)
{
    int d = blockIdx.x * 256 + threadIdx.x;
    int c = blockIdx.y;
    int b = blockIdx.z;
    float Ac[16];
#pragma unroll
    for (int s = 0; s < 16; s++) Ac[s] = -fexp(A_log[d * 16 + s]);
    float h[16];
    size_t o = ((size_t)(b * NCHUNK + c) * 16) * 512 + d;
#pragma unroll
    for (int s = 0; s < 16; s++) h[s] = hinit[o + (size_t)s * 512];
    const float Dsk = Dskip[d];
    int base = b * LL + c * CLEN;
    for (int t = 0; t < CLEN; t++) {
        int row = base + t;
        float dt = dtb[(size_t)row * 512 + d];
        float u  = b2f(ucb[(size_t)row * 512 + d]);
        float du = dt * u;
        const float4* xb = reinterpret_cast<const float4*>(xbc + (size_t)row * 32);
        float Bv[16], Cv[16];
        float4 q;
        q = xb[0]; Bv[0]=q.x; Bv[1]=q.y; Bv[2]=q.z; Bv[3]=q.w;
        q = xb[1]; Bv[4]=q.x; Bv[5]=q.y; Bv[6]=q.z; Bv[7]=q.w;
        q = xb[2]; Bv[8]=q.x; Bv[9]=q.y; Bv[10]=q.z; Bv[11]=q.w;
        q = xb[3]; Bv[12]=q.x; Bv[13]=q.y; Bv[14]=q.z; Bv[15]=q.w;
        q = xb[4]; Cv[0]=q.x; Cv[1]=q.y; Cv[2]=q.z; Cv[3]=q.w;
        q = xb[5]; Cv[4]=q.x; Cv[5]=q.y; Cv[6]=q.z; Cv[7]=q.w;
        q = xb[6]; Cv[8]=q.x; Cv[9]=q.y; Cv[10]=q.z; Cv[11]=q.w;
        q = xb[7]; Cv[12]=q.x; Cv[13]=q.y; Cv[14]=q.z; Cv[15]=q.w;
        float y = 0.f;
#pragma unroll
        for (int s = 0; s < 16; s++) {
            float a = fexp(dt * Ac[s]);
            h[s] = fmaf(a, h[s], du * Bv[s]);
            y = fmaf(h[s], Cv[s], y);
        }
        float z = b2f(xzb[(size_t)row * 1024 + 512 + d]);
        float sz = z / (1.f + fexp(-z));
        yb[(size_t)row * 512 + d] = f2bf((y + u * Dsk) * sz);
    }
}

// =====================================================================
// mean-pool over L (partial, atomics) + final fc3
// =====================================================================
__global__ __launch_bounds__(256) void pool_partial(
    const float* __restrict__ h2, float* __restrict__ pooled)
{
    int t = threadIdx.x;
    int chunk = blockIdx.x;          // 0..15
    int b = blockIdx.y;
    int l0 = chunk * (LL / 16);
    float s = 0.f;
    for (int l = l0; l < l0 + LL / 16; l++)
        s += h2[((size_t)b * LL + l) * D_MODEL + t];
    atomicAdd(&pooled[b * D_MODEL + t], s);
}

__global__ __launch_bounds__(256) void fc3_kernel(
    const float* __restrict__ pooled, const float* __restrict__ w,
    const float* __restrict__ bias, float* __restrict__ out)
{
    __shared__ float red[256];
    int t = threadIdx.x;
    int b = blockIdx.x;
    float p = pooled[b * D_MODEL + t] * (1.0f / LL);
    for (int c = 0; c < NCLS; c++) {
        red[t] = p * w[c * D_MODEL + t];
        __syncthreads();
        for (int off = 128; off > 0; off >>= 1) {
            if (t < off) red[t] += red[t + off];
            __syncthreads();
        }
        if (t == 0) out[b * NCLS + c] = red[0] + bias[c];
        __syncthreads();
    }
}

// =====================================================================
extern "C" void kernel_launch(void* const* d_in, const int* in_sizes, int n_in,
                              void* d_out, int out_size, void* d_ws, size_t ws_size,
                              hipStream_t stream)
{
    const float* x         = (const float*)d_in[0];
    const float* fc1_w     = (const float*)d_in[1];
    const float* fc1_b     = (const float*)d_in[2];
    const float* in_proj_w = (const float*)d_in[3];
    const float* conv_w    = (const float*)d_in[4];
    const float* conv_b    = (const float*)d_in[5];
    const float* x_proj_w  = (const float*)d_in[6];
    const float* dt_proj_w = (const float*)d_in[7];
    const float* dt_proj_b = (const float*)d_in[8];
    const float* A_log     = (const float*)d_in[9];
    const float* D_skip    = (const float*)d_in[10];
    const float* out_proj_w= (const float*)d_in[11];
    const float* fc3_w     = (const float*)d_in[12];
    const float* fc3_b     = (const float*)d_in[13];
    float* out = (float*)d_out;

    char* WS = (char*)d_ws;
    unsigned short* xb16  = (unsigned short*)(WS + OFF_XB16);
    unsigned short* hb    = (unsigned short*)(WS + OFF_HB);
    unsigned short* xzb   = (unsigned short*)(WS + OFF_XZB);
    unsigned short* ucb   = (unsigned short*)(WS + OFF_UCB);
    unsigned short* yb    = (unsigned short*)(WS + OFF_YB);
    float*          dtb   = (float*)(WS + OFF_DT);
    float*          xbc   = (float*)(WS + OFF_XBC);
    float*          hloc  = (float*)(WS + OFF_HLOC);
    float*          Pp    = (float*)(WS + OFF_PP);
    float*          h2    = (float*)(WS + OFF_H2);
    unsigned short* wcat  = (unsigned short*)(WS + OFF_WCAT);
    unsigned short* fc1wb = (unsigned short*)(WS + OFF_FC1WB);
    unsigned short* ipwb  = (unsigned short*)(WS + OFF_IPWB);
    unsigned short* opwb  = (unsigned short*)(WS + OFF_OPWB);
    float*          pooled= (float*)(WS + OFF_POOL);

    // 0. dtype converts (once per call)
    f2b_kernel<<<(BL * 1024 / 8) / 256, 256, 0, stream>>>(x, xb16, BL * 1024 / 8);
    f2b_kernel<<<(256 * 1024 / 8) / 256, 256, 0, stream>>>(fc1_w, fc1wb, 256 * 1024 / 8);
    f2b_kernel<<<(1024 * 256 / 8) / 256, 256, 0, stream>>>(in_proj_w, ipwb, 1024 * 256 / 8);
    f2b_kernel<<<(256 * 512 / 8) / 256, 256, 0, stream>>>(out_proj_w, opwb, 256 * 512 / 8);
    wcat_kernel<<<(544 * 512) / 256, 256, 0, stream>>>(dt_proj_w, x_proj_w, wcat);

    // 1. h = gelu(x @ fc1_w^T + b)            -> bf16 (32768,256)
    gemm_bf16<1, false, 1><<<dim3(256, 2), 256, 0, stream>>>(
        xb16, IN_SZ, fc1wb, IN_SZ, hb, D_MODEL, nullptr, fc1_b, D_MODEL, IN_SZ);
    // 2. xz = h @ in_proj_w^T                 -> bf16 (32768,1024)
    gemm_bf16<0, false, 1><<<dim3(256, 8), 256, 0, stream>>>(
        hb, D_MODEL, ipwb, D_MODEL, xzb, 1024, nullptr, nullptr, 1024, D_MODEL);
    // 3. uc = silu(causal_conv(u) + conv_b)   -> bf16
    conv_silu<<<(BL * D_INNER) / 256, 256, 0, stream>>>(xzb, conv_w, conv_b, ucb);
    // 4+5 fused: [dt|bc] = uc @ wcat^T ; dt->softplus->dtb(f32), bc->xbc(f32)
    gemm_bf16<3, true, 0><<<dim3(256, 5), 256, 0, stream>>>(
        ucb, D_INNER, wcat, D_INNER, dtb, 512, xbc, dt_proj_b, 544, D_INNER);
    // 6-8. chunked selective scan (+ gating fused into pass2 -> yb bf16)
    scan_pass1<<<dim3(2, NCHUNK, BB), 256, 0, stream>>>(dtb, ucb, xbc, A_log, hloc, Pp);
    scan_fixup<<<256, 256, 0, stream>>>(hloc, Pp);
    scan_pass2<<<dim3(2, NCHUNK, BB), 256, 0, stream>>>(dtb, ucb, xbc, xzb, A_log, D_skip, hloc, yb);
    // 9. h2 = y @ out_proj_w^T                -> f32 (32768,256)
    gemm_bf16<0, false, 0><<<dim3(256, 2), 256, 0, stream>>>(
        yb, D_INNER, opwb, D_INNER, h2, D_MODEL, nullptr, nullptr, D_MODEL, D_INNER);
    // 10-12. mean pool + fc3
    hipMemsetAsync(pooled, 0, BB * D_MODEL * sizeof(float), stream);
    pool_partial<<<dim3(16, BB), 256, 0, stream>>>(h2, pooled);
    fc3_kernel<<<BB, 256, 0, stream>>>(pooled, fc3_w, fc3_b, out);
}